// Round 12
// baseline (230.174 us; speedup 1.0000x reference)
//
#include <hip/hip_runtime.h>
#include <hip/hip_bf16.h>

typedef __hip_bfloat16 bf16;
typedef __attribute__((ext_vector_type(8))) short short8b;
typedef __attribute__((ext_vector_type(4))) short short4b;
typedef __attribute__((ext_vector_type(4))) float f32x4;

#define NAREA 2025
#define NAREA_PAD 2048
#define L2E 1.4426950408889634f

static __device__ __forceinline__ float b2f(bf16 x) { return __bfloat162float(x); }
static __device__ __forceinline__ short f2bs(float f) {
  bf16 h = __float2bfloat16(f);
  return *(short*)&h;
}

// async global->LDS, 16B/lane; lds base must be wave-uniform (lane*16 added by HW)
static __device__ __forceinline__ void gll16(const void* g, void* l) {
  __builtin_amdgcn_global_load_lds(
      (const __attribute__((address_space(1))) unsigned int*)(unsigned long long)g,
      (__attribute__((address_space(3))) unsigned int*)(unsigned int)(unsigned long long)l,
      16, 0, 0);
}

// ---------------------------------------------------------------------------
// Fused prep: [0,4800) cast x+wqkv; [4800,6528) transpose-cast wq/wk/wv;
// [6528,6536) rect table.
// ---------------------------------------------------------------------------
__global__ __launch_bounds__(256) void k_prep(
    const float* __restrict__ x, const float* __restrict__ wqkv,
    const float* __restrict__ wq, const float* __restrict__ wk,
    const float* __restrict__ wv,
    bf16* __restrict__ xb, bf16* __restrict__ wqkvb,
    bf16* __restrict__ wqT, bf16* __restrict__ wkT, bf16* __restrict__ wvT,
    int4* __restrict__ rectG, float* __restrict__ invG)
{
  __shared__ float tile[32][33];
  int b = blockIdx.x;
  if (b < 4800) {
    int idx = (b * 256 + threadIdx.x) * 4;
    const int NX = 4096 * 768;
    float4 v;
    bf16* d;
    if (idx < NX) { v = *(const float4*)(x + idx); d = xb + idx; }
    else { v = *(const float4*)(wqkv + (idx - NX)); d = wqkvb + (idx - NX); }
    short4b s = {f2bs(v.x), f2bs(v.y), f2bs(v.z), f2bs(v.w)};
    *(short4b*)d = s;
    return;
  }
  if (b < 6528) {
    int r = b - 4800;
    int z = r / 576; r -= z * 576;
    int by = r / 24, bx = r - by * 24;
    const float* src = (z == 0) ? wq : (z == 1) ? wk : wv;
    bf16* dst = (z == 0) ? wqT : (z == 1) ? wkT : wvT;
    int r0 = by * 32, c0 = bx * 32;
    int lx = threadIdx.x & 31, ly = threadIdx.x >> 5;
#pragma unroll
    for (int yy = 0; yy < 4; ++yy)
      tile[ly + yy * 8][lx] = src[(size_t)(r0 + ly + yy * 8) * 768 + c0 + lx];
    __syncthreads();
#pragma unroll
    for (int yy = 0; yy < 4; ++yy)
      dst[(size_t)(c0 + ly + yy * 8) * 768 + r0 + lx] =
          __float2bfloat16(tile[lx][ly + yy * 8]);
    return;
  }
  int m = (b - 6528) * 256 + threadIdx.x;
  if (m >= NAREA_PAD) return;
  int4 rc = make_int4(0, 0, 0, 0);
  float iv = 0.f;
  if (m < NAREA) {
    int rem = m, ah = 1, aw = 1, found = 0;
    for (int a = 1; a <= 3 && !found; ++a)
      for (int w = 1; w <= 3 && !found; ++w) {
        int np = (17 - a) * (17 - w);
        if (rem < np) { ah = a; aw = w; found = 1; }
        else rem -= np;
      }
    int cw = 17 - aw;
    int y = rem / cw, xx = rem - y * cw;
    rc.x = (y * 17 + xx) * 64;
    rc.y = (y * 17 + (xx + aw)) * 64;
    rc.z = ((y + ah) * 17 + xx) * 64;
    rc.w = ((y + ah) * 17 + (xx + aw)) * 64;
    iv = 1.0f / (float)(ah * aw);
  }
  rectG[m] = rc;
  invG[m] = iv;
}

// ---------------------------------------------------------------------------
// Transpose-cast 768x768 fp32 -> bf16 (fallback path only; primary folds
// this into k_norm2t).
// ---------------------------------------------------------------------------
__global__ __launch_bounds__(256) void k_tcast1(
    const float* __restrict__ src, bf16* __restrict__ dst)
{
  __shared__ float tile[32][33];
  int r0 = blockIdx.y * 32, c0 = blockIdx.x * 32;
  int lx = threadIdx.x & 31, ly = threadIdx.x >> 5;
#pragma unroll
  for (int yy = 0; yy < 4; ++yy)
    tile[ly + yy * 8][lx] = src[(size_t)(r0 + ly + yy * 8) * 768 + c0 + lx];
  __syncthreads();
#pragma unroll
  for (int yy = 0; yy < 4; ++yy)
    dst[(size_t)(c0 + ly + yy * 8) * 768 + r0 + lx] =
        __float2bfloat16(tile[lx][ly + yy * 8]);
}

// ===========================================================================
// MFMA GEMM cores (m97 staging pattern). Tiles per r9. r12: k_proj/k_out use
// SWAPPED operand order mfma(B,A) so reg-axis = contiguous output dim
// (reg -> FIRST operand rows, col=lane&15 -> SECOND; verified vs k_combine)
// => vectorized epilogue stores (proj 32->8, out 16->4 per thread).
// ===========================================================================

// Wc^T[t][n][m] (bf16) = (wqkv[:,t] @ w_{q,k,v})^T ; 64x64 tile
__global__ __launch_bounds__(256) void k_combine_m(
    const bf16* __restrict__ wqkvb, const bf16* __restrict__ wqT,
    const bf16* __restrict__ wkT, const bf16* __restrict__ wvT,
    bf16* __restrict__ WcTb)
{
  __shared__ __align__(16) short As[2][64 * 32];
  __shared__ __align__(16) short Bs[2][64 * 32];
  const int t3 = blockIdx.z;
  const bf16* BT = (t3 == 0) ? wqT : (t3 == 1) ? wkT : wvT;
  const int m0 = blockIdx.y * 64, n0 = blockIdx.x * 64;
  const int tid = threadIdx.x, lane = tid & 63, w = tid >> 6;
  const int tt = lane & 15, q4 = lane >> 4;
  const int moff = (w & 1) * 32, noff = (w >> 1) * 32;
  const int r_a = tid >> 2, kc = (tid & 3) * 8;

  f32x4 acc[2][2];
#pragma unroll
  for (int i = 0; i < 2; ++i)
#pragma unroll
    for (int j = 0; j < 2; ++j) acc[i][j] = (f32x4){0.f, 0.f, 0.f, 0.f};

#define STAGE_C(k0, buf)                                                        \
  {                                                                             \
    gll16(wqkvb + (size_t)(m0 + r_a) * 2304 + t3 * 768 + (k0) + kc,             \
          &As[buf][w * 512]);                                                   \
    gll16(BT + (size_t)(n0 + r_a) * 768 + (k0) + kc, &Bs[buf][w * 512]);        \
  }

  STAGE_C(0, 0);
  for (int it = 0; it < 24; ++it) {
    __syncthreads();
    if (it < 23) STAGE_C((it + 1) * 32, (it + 1) & 1);
    const short* as = As[it & 1];
    const short* bs = Bs[it & 1];
    short8b afr[2], bfr[2];
#pragma unroll
    for (int mt = 0; mt < 2; ++mt)
      afr[mt] = *(const short8b*)&as[(moff + mt * 16 + tt) * 32 + q4 * 8];
#pragma unroll
    for (int nt = 0; nt < 2; ++nt)
      bfr[nt] = *(const short8b*)&bs[(noff + nt * 16 + tt) * 32 + q4 * 8];
#pragma unroll
    for (int mt = 0; mt < 2; ++mt)
#pragma unroll
      for (int nt = 0; nt < 2; ++nt)
        acc[mt][nt] = __builtin_amdgcn_mfma_f32_16x16x32_bf16(afr[mt], bfr[nt], acc[mt][nt], 0, 0, 0);
  }
#undef STAGE_C

  bf16* C = WcTb + (size_t)t3 * 768 * 768;
#pragma unroll
  for (int nt = 0; nt < 2; ++nt) {
    int n = n0 + noff + nt * 16 + tt;
#pragma unroll
    for (int mt = 0; mt < 2; ++mt) {
      int mb = m0 + moff + mt * 16 + q4 * 4;
      short4b v = {f2bs(acc[mt][nt][0]), f2bs(acc[mt][nt][1]),
                   f2bs(acc[mt][nt][2]), f2bs(acc[mt][nt][3])};
      *(short4b*)&C[(size_t)n * 768 + mb] = v;
    }
  }
}

// qh/kh/vh = xb @ Wc[t] + bias, scattered to [(b*12+h)][n][d] bf16 ; 128x64
// SWAPPED mfma: reg -> c (contiguous d) => short4b stores.
__global__ __launch_bounds__(256) void k_proj_m(
    const bf16* __restrict__ xb, const bf16* __restrict__ WcTb,
    const float* __restrict__ bq, const float* __restrict__ bk,
    const float* __restrict__ bv,
    bf16* __restrict__ qh, bf16* __restrict__ kh, bf16* __restrict__ vh)
{
  __shared__ __align__(16) short As[2][128 * 32];
  __shared__ __align__(16) short Bs[2][64 * 32];
  const int t3 = blockIdx.z;
  const bf16* BT = WcTb + (size_t)t3 * 768 * 768;
  const float* bias = (t3 == 0) ? bq : (t3 == 1) ? bk : bv;
  bf16* dst = (t3 == 0) ? qh : (t3 == 1) ? kh : vh;
  const int m0 = blockIdx.y * 128, n0 = blockIdx.x * 64;
  const int tid = threadIdx.x, lane = tid & 63, w = tid >> 6;
  const int tt = lane & 15, q4 = lane >> 4;
  const int moff = (w & 1) * 64, noff = (w >> 1) * 32;
  const int r_a = tid >> 2, kc = (tid & 3) * 8;

  f32x4 acc[4][2];
#pragma unroll
  for (int i = 0; i < 4; ++i)
#pragma unroll
    for (int j = 0; j < 2; ++j) acc[i][j] = (f32x4){0.f, 0.f, 0.f, 0.f};

#define STAGE_P(k0, buf)                                                        \
  {                                                                             \
    gll16(xb + (size_t)(m0 + r_a) * 768 + (k0) + kc, &As[buf][w * 512]);        \
    gll16(xb + (size_t)(m0 + r_a + 64) * 768 + (k0) + kc,                       \
          &As[buf][2048 + w * 512]);                                            \
    gll16(BT + (size_t)(n0 + r_a) * 768 + (k0) + kc, &Bs[buf][w * 512]);        \
  }

  STAGE_P(0, 0);
  for (int it = 0; it < 24; ++it) {
    __syncthreads();
    if (it < 23) STAGE_P((it + 1) * 32, (it + 1) & 1);
    const short* as = As[it & 1];
    const short* bs = Bs[it & 1];
    short8b afr[4], bfr[2];
#pragma unroll
    for (int mt = 0; mt < 4; ++mt)
      afr[mt] = *(const short8b*)&as[(moff + mt * 16 + tt) * 32 + q4 * 8];
#pragma unroll
    for (int nt = 0; nt < 2; ++nt)
      bfr[nt] = *(const short8b*)&bs[(noff + nt * 16 + tt) * 32 + q4 * 8];
#pragma unroll
    for (int mt = 0; mt < 4; ++mt)
#pragma unroll
      for (int nt = 0; nt < 2; ++nt)
        acc[mt][nt] = __builtin_amdgcn_mfma_f32_16x16x32_bf16(bfr[nt], afr[mt], acc[mt][nt], 0, 0, 0);
  }
#undef STAGE_P

#pragma unroll
  for (int mt = 0; mt < 4; ++mt) {
    int m = m0 + moff + mt * 16 + tt;
    size_t mb = (((size_t)((m >> 8) * 12)) << 14) + ((m & 255) << 6);
#pragma unroll
    for (int nt = 0; nt < 2; ++nt) {
      int c0 = n0 + noff + nt * 16 + q4 * 4;
      int h = c0 >> 6, d0 = c0 & 63;
      float4 bv4 = *(const float4*)&bias[c0];
      short4b v = {f2bs(acc[mt][nt][0] + bv4.x), f2bs(acc[mt][nt][1] + bv4.y),
                   f2bs(acc[mt][nt][2] + bv4.z), f2bs(acc[mt][nt][3] + bv4.w)};
      *(short4b*)&dst[mb + (((size_t)h) << 14) + d0] = v;
    }
  }
}

// out = gather(attno) @ wo + bo (fp32 out) ; 64x64 tile
// SWAPPED mfma: reg -> c (contiguous) => float4 stores.
__global__ __launch_bounds__(256) void k_out_m(
    const bf16* __restrict__ attno, const bf16* __restrict__ woT,
    const float* __restrict__ bo, float* __restrict__ out)
{
  __shared__ __align__(16) short As[2][64 * 32];
  __shared__ __align__(16) short Bs[2][64 * 32];
  const int m0 = blockIdx.y * 64, n0 = blockIdx.x * 64;
  const int tid = threadIdx.x, lane = tid & 63, w = tid >> 6;
  const int tt = lane & 15, q4 = lane >> 4;
  const int moff = (w & 1) * 32, noff = (w >> 1) * 32;
  const int r_a = tid >> 2, kc = (tid & 3) * 8;
  const int m_a0 = m0 + r_a;

  f32x4 acc[2][2];
#pragma unroll
  for (int i = 0; i < 2; ++i)
#pragma unroll
    for (int j = 0; j < 2; ++j) acc[i][j] = (f32x4){0.f, 0.f, 0.f, 0.f};

#define STAGE_O(k0, buf)                                                        \
  {                                                                             \
    int k = (k0) + kc;                                                          \
    gll16(attno + (((size_t)((m_a0 >> 8) * 12 + (k >> 6))) << 14) +             \
              ((m_a0 & 255) << 6) + (k & 63),                                   \
          &As[buf][w * 512]);                                                   \
    gll16(woT + (size_t)(n0 + r_a) * 768 + k, &Bs[buf][w * 512]);               \
  }

  STAGE_O(0, 0);
  for (int it = 0; it < 24; ++it) {
    __syncthreads();
    if (it < 23) STAGE_O((it + 1) * 32, (it + 1) & 1);
    const short* as = As[it & 1];
    const short* bs = Bs[it & 1];
    short8b afr[2], bfr[2];
#pragma unroll
    for (int mt = 0; mt < 2; ++mt)
      afr[mt] = *(const short8b*)&as[(moff + mt * 16 + tt) * 32 + q4 * 8];
#pragma unroll
    for (int nt = 0; nt < 2; ++nt)
      bfr[nt] = *(const short8b*)&bs[(noff + nt * 16 + tt) * 32 + q4 * 8];
#pragma unroll
    for (int mt = 0; mt < 2; ++mt)
#pragma unroll
      for (int nt = 0; nt < 2; ++nt)
        acc[mt][nt] = __builtin_amdgcn_mfma_f32_16x16x32_bf16(bfr[nt], afr[mt], acc[mt][nt], 0, 0, 0);
  }
#undef STAGE_O

#pragma unroll
  for (int mt = 0; mt < 2; ++mt) {
    int m = m0 + moff + mt * 16 + tt;
#pragma unroll
    for (int nt = 0; nt < 2; ++nt) {
      int c0 = n0 + noff + nt * 16 + q4 * 4;
      float4 bv4 = *(const float4*)&bo[c0];
      float4 o = {acc[mt][nt][0] + bv4.x, acc[mt][nt][1] + bv4.y,
                  acc[mt][nt][2] + bv4.z, acc[mt][nt][3] + bv4.w};
      *(float4*)&out[(size_t)m * 768 + c0] = o;
    }
  }
}

// ---------------------------------------------------------------------------
// PRIMARY path: SAT in LDS + materialize pooled areas (r11-verified).
// ---------------------------------------------------------------------------
__global__ __launch_bounds__(1024) void k_area_pre(
    const bf16* __restrict__ kh, const bf16* __restrict__ vh,
    const int4* __restrict__ rectG, const float* __restrict__ invG,
    bf16* __restrict__ Karea, bf16* __restrict__ VareaT)
{
  __shared__ float sat[17 * 17 * 65];
  int bh = blockIdx.x >> 1;
  bool isv = blockIdx.x & 1;
  const bf16* src = (isv ? vh : kh) + ((size_t)bh << 14);
  int tid = threadIdx.x;
  int d = tid & 63;
  int row = tid >> 6;
  {
    float run = 0.f;
    sat[((row + 1) * 17) * 65 + d] = 0.f;
#pragma unroll
    for (int xx = 0; xx < 16; ++xx) {
      run += b2f(src[(row * 16 + xx) * 64 + d]);
      sat[((row + 1) * 17 + (xx + 1)) * 65 + d] = run;
    }
    if (row == 0) {
#pragma unroll
      for (int xx = 0; xx < 17; ++xx) sat[xx * 65 + d] = 0.f;
    }
  }
  __syncthreads();
  {
    int x = row + 1;
    float run = 0.f;
#pragma unroll
    for (int y = 1; y <= 16; ++y) {
      run += sat[(y * 17 + x) * 65 + d];
      sat[(y * 17 + x) * 65 + d] = run;
    }
  }
  __syncthreads();
  if (!isv) {
    // K band-sliding: wave = (y,ah) combo (45 total), lane = d.
    bf16* out = Karea + ((size_t)bh << 17);   // bh*2048*64
    for (int c = row; c < 45; c += 16) {
      int ah, y;
      if (c < 16)      { ah = 1; y = c; }
      else if (c < 31) { ah = 2; y = c - 16; }
      else             { ah = 3; y = c - 31; }
      int b1, b2, b3;
      if (ah == 1)      { b1 = 0;    b2 = 256;  b3 = 496;  }
      else if (ah == 2) { b1 = 720;  b2 = 960;  b3 = 1185; }
      else              { b1 = 1395; b2 = 1619; b3 = 1829; }
      float V[17];
#pragma unroll
      for (int x = 0; x < 17; ++x)
        V[x] = sat[((y + ah) * 17 + x) * 65 + d] - sat[(y * 17 + x) * 65 + d];
      {
        int b = b1 + y * 16;
        float iv = L2E / (float)ah;
#pragma unroll
        for (int x = 0; x < 16; ++x)
          out[(size_t)(b + x) * 64 + d] = __float2bfloat16((V[x + 1] - V[x]) * iv);
      }
      {
        int b = b2 + y * 15;
        float iv = L2E / (float)(2 * ah);
#pragma unroll
        for (int x = 0; x < 15; ++x)
          out[(size_t)(b + x) * 64 + d] = __float2bfloat16((V[x + 2] - V[x]) * iv);
      }
      {
        int b = b3 + y * 14;
        float iv = L2E / (float)(3 * ah);
#pragma unroll
        for (int x = 0; x < 14; ++x)
          out[(size_t)(b + x) * 64 + d] = __float2bfloat16((V[x + 3] - V[x]) * iv);
      }
    }
    if (row == 15) {
      for (int m = NAREA; m < NAREA_PAD; ++m)
        out[(size_t)m * 64 + d] = __float2bfloat16(0.f);
    }
  } else {
    // V: sum-pooled, transposed [it][d][m]; lanes span m -> coalesced 2B
    // stores. it-outer: one rectG load + corner rescale per (it,mcol).
    int mcol = tid & 63;
    int r16 = tid >> 6;             // 0..15
    bf16* out = VareaT + ((size_t)bh << 17);
    for (int it = 0; it < 32; ++it) {
      int4 rc = rectG[it * 64 + mcol];
      int cx = rc.x + (rc.x >> 6), cy = rc.y + (rc.y >> 6);
      int cz = rc.z + (rc.z >> 6), cw = rc.w + (rc.w >> 6);
#pragma unroll
      for (int j = 0; j < 4; ++j) {
        int dd = r16 + j * 16;
        float df = sat[cw + dd] - sat[cy + dd] - sat[cz + dd] + sat[cx + dd];
        out[(((size_t)it << 6) + dd) * 64 + mcol] = __float2bfloat16(df);
      }
    }
  }
}

// ---------------------------------------------------------------------------
// PRIMARY attention (r11 + PV operand swap): 256-thr / 4-wave, 32 q/wave,
// area-split 2x, grid (192,2,2) = 768 blocks = 3/CU, additive partials.
// p = v_exp_f32(s) (log2e pre-folded into Karea).
// PV: O = mfma(vf, apv) => reg -> d (contiguous) => f32x4 partial stores
// (32 scalar -> 8 vector per thread); apv/vf fragments unchanged (A and B
// lane layouts are identical for 16x16x32).
// ---------------------------------------------------------------------------
__global__ __launch_bounds__(256, 4) void k_attn_g(
    const bf16* __restrict__ qh, const bf16* __restrict__ Karea,
    const bf16* __restrict__ VareaT,
    float* __restrict__ Op0, float* __restrict__ Op1,
    float* __restrict__ lp0, float* __restrict__ lp1)
{
  __shared__ __align__(16) short aK2[2][64 * 80];
  __shared__ __align__(16) short aVt2[2][64 * 80];

  const int tid = threadIdx.x;
  const int w = tid >> 6;            // 0..3
  const int lane = tid & 63;
  const int t = lane & 15;
  const int q4 = lane >> 4;
  const int bh = blockIdx.x;
  const int Q0 = blockIdx.y * 128;
  const int it0 = blockIdx.z * 16;   // area half: tiles [it0, it0+16)
  const int rbase = (t & 12) * 2 + (t & 3);

  const bf16* Kb = Karea + ((size_t)bh << 17);
  const bf16* Vb = VareaT + ((size_t)bh << 17);
  const bf16* qrowA = qh + ((size_t)bh << 14) + (size_t)(Q0 + w * 32 + t) * 64;
  const bf16* qrowB = qrowA + 16 * 64;

  short8b qfA0 = *(const short8b*)(qrowA + q4 * 8);
  short8b qfA1 = *(const short8b*)(qrowA + 32 + q4 * 8);
  short8b qfB0 = *(const short8b*)(qrowB + q4 * 8);
  short8b qfB1 = *(const short8b*)(qrowB + 32 + q4 * 8);

  f32x4 OA[4], OB[4];
#pragma unroll
  for (int i = 0; i < 4; ++i) {
    OA[i] = (f32x4){0.f, 0.f, 0.f, 0.f};
    OB[i] = (f32x4){0.f, 0.f, 0.f, 0.f};
  }
  float lA = 0.f, lB = 0.f;

  const int a8 = tid >> 2;           // 0..63: area slot (K) / d row (V)
  const int c8 = (tid & 3) * 16;     // col start (elements); each thr 2x8

  {
    size_t off = ((size_t)(it0 * 64 + a8) << 6) + c8;
    short8b k0a = *(const short8b*)&Kb[off];
    short8b k0b = *(const short8b*)&Kb[off + 8];
    short8b v0a = *(const short8b*)&Vb[off];
    short8b v0b = *(const short8b*)&Vb[off + 8];
    *(short8b*)&aK2[0][a8 * 80 + c8] = k0a;
    *(short8b*)&aK2[0][a8 * 80 + c8 + 8] = k0b;
    *(short8b*)&aVt2[0][a8 * 80 + c8] = v0a;
    *(short8b*)&aVt2[0][a8 * 80 + c8 + 8] = v0b;
  }

  for (int it = it0; it < it0 + 16; ++it) {
    short8b kna, knb, vna, vnb;
    if (it + 1 < it0 + 16) {
      size_t off = ((size_t)((it + 1) * 64 + a8) << 6) + c8;
      kna = *(const short8b*)&Kb[off];
      knb = *(const short8b*)&Kb[off + 8];
      vna = *(const short8b*)&Vb[off];
      vnb = *(const short8b*)&Vb[off + 8];
    }
    __syncthreads();
    const short* aK = aK2[it & 1];
    const short* aVt = aVt2[it & 1];
    if (it + 1 < it0 + 16) {
      short* aKn = aK2[(it + 1) & 1];
      short* aVtn = aVt2[(it + 1) & 1];
      *(short8b*)&aKn[a8 * 80 + c8] = kna;
      *(short8b*)&aKn[a8 * 80 + c8 + 8] = knb;
      *(short8b*)&aVtn[a8 * 80 + c8] = vna;
      *(short8b*)&aVtn[a8 * 80 + c8 + 8] = vnb;
    }

    const int t0 = it * 64;
    const bool edge = (t0 + 64 > NAREA);
    union { short8b v; unsigned u[4]; } apvA[2], apvB[2];
#pragma unroll
    for (int at = 0; at < 4; ++at) {
      int row = rbase + (at & 1) * 4 + (at >> 1) * 32;
      short8b af0 = *(const short8b*)&aK[row * 80 + q4 * 8];
      short8b af1 = *(const short8b*)&aK[row * 80 + 32 + q4 * 8];
      int abase = t0 + (at >> 1) * 32 + q4 * 8 + (at & 1) * 4;
      {
        f32x4 s = (f32x4){0.f, 0.f, 0.f, 0.f};
        s = __builtin_amdgcn_mfma_f32_16x16x32_bf16(af0, qfA0, s, 0, 0, 0);
        s = __builtin_amdgcn_mfma_f32_16x16x32_bf16(af1, qfA1, s, 0, 0, 0);
        float p[4];
#pragma unroll
        for (int r = 0; r < 4; ++r) {
          p[r] = __builtin_amdgcn_exp2f(s[r]);
          if (edge && (abase + r >= NAREA)) p[r] = 0.f;
        }
        lA += (p[0] + p[1]) + (p[2] + p[3]);
        unsigned lo = ((unsigned)(unsigned short)f2bs(p[1]) << 16) |
                      (unsigned short)f2bs(p[0]);
        unsigned hi = ((unsigned)(unsigned short)f2bs(p[3]) << 16) |
                      (unsigned short)f2bs(p[2]);
        apvA[at >> 1].u[(at & 1) * 2 + 0] = lo;
        apvA[at >> 1].u[(at & 1) * 2 + 1] = hi;
      }
      {
        f32x4 s = (f32x4){0.f, 0.f, 0.f, 0.f};
        s = __builtin_amdgcn_mfma_f32_16x16x32_bf16(af0, qfB0, s, 0, 0, 0);
        s = __builtin_amdgcn_mfma_f32_16x16x32_bf16(af1, qfB1, s, 0, 0, 0);
        float p[4];
#pragma unroll
        for (int r = 0; r < 4; ++r) {
          p[r] = __builtin_amdgcn_exp2f(s[r]);
          if (edge && (abase + r >= NAREA)) p[r] = 0.f;
        }
        lB += (p[0] + p[1]) + (p[2] + p[3]);
        unsigned lo = ((unsigned)(unsigned short)f2bs(p[1]) << 16) |
                      (unsigned short)f2bs(p[0]);
        unsigned hi = ((unsigned)(unsigned short)f2bs(p[3]) << 16) |
                      (unsigned short)f2bs(p[2]);
        apvB[at >> 1].u[(at & 1) * 2 + 0] = lo;
        apvB[at >> 1].u[(at & 1) * 2 + 1] = hi;
      }
    }
#pragma unroll
    for (int nt = 0; nt < 4; ++nt) {
      short8b vf0 = *(const short8b*)&aVt[(nt * 16 + t) * 80 + q4 * 8];
      short8b vf1 = *(const short8b*)&aVt[(nt * 16 + t) * 80 + 32 + q4 * 8];
      OA[nt] = __builtin_amdgcn_mfma_f32_16x16x32_bf16(vf0, apvA[0].v, OA[nt], 0, 0, 0);
      OA[nt] = __builtin_amdgcn_mfma_f32_16x16x32_bf16(vf1, apvA[1].v, OA[nt], 0, 0, 0);
      OB[nt] = __builtin_amdgcn_mfma_f32_16x16x32_bf16(vf0, apvB[0].v, OB[nt], 0, 0, 0);
      OB[nt] = __builtin_amdgcn_mfma_f32_16x16x32_bf16(vf1, apvB[1].v, OB[nt], 0, 0, 0);
    }
  }

  lA += __shfl_xor(lA, 16, 64);
  lA += __shfl_xor(lA, 32, 64);
  lB += __shfl_xor(lB, 16, 64);
  lB += __shfl_xor(lB, 32, 64);

  float* lp = blockIdx.z ? lp1 : lp0;
  float* Op = blockIdx.z ? Op1 : Op0;
  if (q4 == 0) {
    lp[(bh << 8) + Q0 + w * 32 + t] = lA;
    lp[(bh << 8) + Q0 + w * 32 + 16 + t] = lB;
  }
  // swapped-PV layout: thread holds O[q = t (A) / 16+t (B)][d = nt*16+q4*4+r]
  float* Ob = Op + (((size_t)(bh << 8) + Q0 + w * 32) << 6);
#pragma unroll
  for (int nt = 0; nt < 4; ++nt) {
    *(f32x4*)&Ob[(size_t)t * 64 + nt * 16 + q4 * 4] = OA[nt];
    *(f32x4*)&Ob[(size_t)(16 + t) * 64 + nt * 16 + q4 * 4] = OB[nt];
  }
}

// ---------------------------------------------------------------------------
// Combine area-half partials + (folded) wo transpose-cast.
// blocks [0,3072): attno = (O0+O1)/(l0+l1); blocks [3072,3648): tcast wo.
// ---------------------------------------------------------------------------
__global__ __launch_bounds__(256) void k_norm2t(
    const float* __restrict__ Op0, const float* __restrict__ Op1,
    const float* __restrict__ lp0, const float* __restrict__ lp1,
    bf16* __restrict__ attno,
    const float* __restrict__ wo, bf16* __restrict__ woT)
{
  if (blockIdx.x < 3072) {
    int i = (blockIdx.x * 256 + threadIdx.x) * 4;
    f32x4 a = *(const f32x4*)(Op0 + i);
    f32x4 b = *(const f32x4*)(Op1 + i);
    int q = i >> 6;
    float invl = 1.0f / (lp0[q] + lp1[q]);
    short4b s = {f2bs((a[0] + b[0]) * invl), f2bs((a[1] + b[1]) * invl),
                 f2bs((a[2] + b[2]) * invl), f2bs((a[3] + b[3]) * invl)};
    *(short4b*)(attno + i) = s;
    return;
  }
  __shared__ float tile[32][33];
  int b = blockIdx.x - 3072;
  int bxx = b % 24, byy = b / 24;
  int r0 = byy * 32, c0 = bxx * 32;
  int lx = threadIdx.x & 31, ly = threadIdx.x >> 5;
#pragma unroll
  for (int yy = 0; yy < 4; ++yy)
    tile[ly + yy * 8][lx] = wo[(size_t)(r0 + ly + yy * 8) * 768 + c0 + lx];
  __syncthreads();
#pragma unroll
  for (int yy = 0; yy < 4; ++yy)
    woT[(size_t)(c0 + ly + yy * 8) * 768 + r0 + lx] =
        __float2bfloat16(tile[lx][ly + yy * 8]);
}

// ---------------------------------------------------------------------------
// FALLBACK path (ws too small for materialized areas): round-0 verbatim.
// ---------------------------------------------------------------------------
__global__ __launch_bounds__(1024) void k_integral_p(
    const bf16* __restrict__ kh, const bf16* __restrict__ vh,
    float* __restrict__ Ik, float* __restrict__ Iv)
{
  __shared__ float sat[17 * 17 * 64];
  int bh = blockIdx.x >> 1;
  bool isv = blockIdx.x & 1;
  const bf16* src = (isv ? vh : kh) + ((size_t)bh << 14);
  float* dst = (isv ? Iv : Ik) + (size_t)bh * 18496;
  int tid = threadIdx.x;
  int d = tid & 63;
  int row = tid >> 6;
  {
    float run = 0.f;
    sat[((row + 1) * 17) * 64 + d] = 0.f;
#pragma unroll
    for (int xx = 0; xx < 16; ++xx) {
      run += b2f(src[(row * 16 + xx) * 64 + d]);
      sat[((row + 1) * 17 + (xx + 1)) * 64 + d] = run;
    }
    if (row == 0) {
#pragma unroll
      for (int xx = 0; xx < 17; ++xx) sat[xx * 64 + d] = 0.f;
    }
  }
  __syncthreads();
  {
    int x = row + 1;
    float run = 0.f;
#pragma unroll
    for (int y = 1; y <= 16; ++y) {
      run += sat[(y * 17 + x) * 64 + d];
      sat[(y * 17 + x) * 64 + d] = run;
    }
  }
  __syncthreads();
  for (int i = tid; i < 18496; i += 1024) dst[i] = sat[i];
}

__global__ __launch_bounds__(1024) void k_attn_m(
    const bf16* __restrict__ qh, const float* __restrict__ Ik,
    const float* __restrict__ Iv, const int4* __restrict__ rectG,
    const float* __restrict__ invG, bf16* __restrict__ attno)
{
  __shared__ __align__(16) short aK2[2][64 * 80];
  __shared__ __align__(16) short aVt2[2][64 * 72];

  const int tid = threadIdx.x;
  const int lane = tid & 63;
  const int w = tid >> 6;
  const int t = lane & 15;
  const int q4 = lane >> 4;
  const int bh = blockIdx.x;
  const int rbase = (t & 12) * 2 + (t & 3);

  const float* Ikb = Ik + (size_t)bh * 18496;
  const float* Ivb = Iv + (size_t)bh * 18496;
  const bf16* qbase = qh + ((size_t)bh << 14);

  short8b qf0 = *(const short8b*)(qbase + (w * 16 + t) * 64 + q4 * 8);
  short8b qf1 = *(const short8b*)(qbase + (w * 16 + t) * 64 + 32 + q4 * 8);

  f32x4 O[4];
#pragma unroll
  for (int i = 0; i < 4; ++i) O[i] = (f32x4){0.f, 0.f, 0.f, 0.f};
  float l = 0.f;

  {
    short* aK = aK2[0];
    short* aVt = aVt2[0];
    short vp[4];
#pragma unroll
    for (int i = 0; i < 4; ++i) {
      int j = w * 4 + i;
      int4 rc = rectG[j];
      float iv = invG[j];
      float kc = Ikb[rc.w + lane] - Ikb[rc.y + lane] - Ikb[rc.z + lane] + Ikb[rc.x + lane];
      float vc = Ivb[rc.w + lane] - Ivb[rc.y + lane] - Ivb[rc.z + lane] + Ivb[rc.x + lane];
      aK[j * 80 + lane] = f2bs(kc * iv);
      vp[i] = f2bs(vc);
    }
    *(short4b*)&aVt[lane * 72 + w * 4] = (short4b){vp[0], vp[1], vp[2], vp[3]};
  }

  float kcr[4], vcr[4], ivr[4];
  for (int it = 0; it < 32; ++it) {
    if (it + 1 < 32) {
      int t0n = (it + 1) * 64;
#pragma unroll
      for (int i = 0; i < 4; ++i) {
        int j = t0n + w * 4 + i;
        int4 rc = rectG[j];
        ivr[i] = invG[j];
        kcr[i] = Ikb[rc.w + lane] - Ikb[rc.y + lane] - Ikb[rc.z + lane] + Ikb[rc.x + lane];
        vcr[i] = Ivb[rc.w + lane] - Ivb[rc.y + lane] - Ivb[rc.z + lane] + Ivb[rc.x + lane];
      }
    }
    __syncthreads();
    const short* aK = aK2[it & 1];
    const short* aVt = aVt2[it & 1];
    if (it + 1 < 32) {
      short* aKn = aK2[(it + 1) & 1];
      short* aVtn = aVt2[(it + 1) & 1];
      short vp[4];
#pragma unroll
      for (int i = 0; i < 4; ++i) {
        aKn[(w * 4 + i) * 80 + lane] = f2bs(kcr[i] * ivr[i]);
        vp[i] = f2bs(vcr[i]);
      }
      *(short4b*)&aVtn[lane * 72 + w * 4] = (short4b){vp[0], vp[1], vp[2], vp[3]};
    }

    const int t0 = it * 64;
    const bool edge = (t0 + 64 > NAREA);
    union { short8b v; unsigned u[4]; } apv[2];
#pragma unroll
    for (int at = 0; at < 4; ++at) {
      int row = rbase + (at & 1) * 4 + (at >> 1) * 32;
      short8b af0 = *(const short8b*)&aK[row * 80 + q4 * 8];
      short8b af1 = *(const short8b*)&aK[row * 80 + 32 + q4 * 8];
      f32x4 s = (f32x4){0.f, 0.f, 0.f, 0.f};
      s = __builtin_amdgcn_mfma_f32_16x16x32_bf16(af0, qf0, s, 0, 0, 0);
      s = __builtin_amdgcn_mfma_f32_16x16x32_bf16(af1, qf1, s, 0, 0, 0);
      int abase = t0 + (at >> 1) * 32 + q4 * 8 + (at & 1) * 4;
      float p[4];
#pragma unroll
      for (int r = 0; r < 4; ++r) {
        p[r] = __expf(s[r]);
        if (edge && (abase + r >= NAREA)) p[r] = 0.f;
      }
      l += (p[0] + p[1]) + (p[2] + p[3]);
      unsigned lo = ((unsigned)(unsigned short)f2bs(p[1]) << 16) |
                    (unsigned short)f2bs(p[0]);
      unsigned hi = ((unsigned)(unsigned short)f2bs(p[3]) << 16) |
                    (unsigned short)f2bs(p[2]);
      apv[at >> 1].u[(at & 1) * 2 + 0] = lo;
      apv[at >> 1].u[(at & 1) * 2 + 1] = hi;
    }
#pragma unroll
    for (int nt = 0; nt < 4; ++nt) {
      short8b vf0 = *(const short8b*)&aVt[(nt * 16 + t) * 72 + q4 * 8];
      short8b vf1 = *(const short8b*)&aVt[(nt * 16 + t) * 72 + 32 + q4 * 8];
      O[nt] = __builtin_amdgcn_mfma_f32_16x16x32_bf16(apv[0].v, vf0, O[nt], 0, 0, 0);
      O[nt] = __builtin_amdgcn_mfma_f32_16x16x32_bf16(apv[1].v, vf1, O[nt], 0, 0, 0);
    }
  }

  l += __shfl_xor(l, 16, 64);
  l += __shfl_xor(l, 32, 64);

  bf16* ob = attno + ((size_t)bh << 14);
#pragma unroll
  for (int r = 0; r < 4; ++r) {
    int qrow = q4 * 4 + r;
    float invl = 1.0f / __shfl(l, qrow, 64);
#pragma unroll
    for (int nt = 0; nt < 4; ++nt)
      ob[(w * 16 + qrow) * 64 + nt * 16 + t] = __float2bfloat16(O[nt][r] * invl);
  }
}

extern "C" void kernel_launch(void* const* d_in, const int* in_sizes, int n_in,
                              void* d_out, int out_size, void* d_ws, size_t ws_size,
                              hipStream_t stream) {
  const float* x    = (const float*)d_in[0];
  const float* wqkv = (const float*)d_in[1];
  const float* wq   = (const float*)d_in[2];
  const float* bq   = (const float*)d_in[3];
  const float* wk   = (const float*)d_in[4];
  const float* bk   = (const float*)d_in[5];
  const float* wv   = (const float*)d_in[6];
  const float* bv   = (const float*)d_in[7];
  const float* wo   = (const float*)d_in[8];
  const float* bo   = (const float*)d_in[9];
  float* out = (float*)d_out;

  char* ws = (char*)d_ws;
  char* ob = (char*)d_out;
  const size_t WC_B = 7077888;   // zone A size
  const size_t QH_B = 6291456;   // bf16 [192][256][64]
  const size_t AREA_B = 50331648; // bf16 [192][2048][64]

  // d_out as scratch: xb + WcTb (dead after k_proj_m), then Op0 (f32 attn
  // partial, = out_size), consumed by k_norm2t before k_out_m writes out.
  bf16* xb    = (bf16*)ob;                  // [0, 6291456)
  bf16* WcTb  = (bf16*)(ob + QH_B);         // [6291456, 9830400)
  float* Op0  = (float*)ob;                 // full 12582912 B
  // ws zone A: attno [0,6291456), rectG/invG, lp0/lp1
  bf16* attno = (bf16*)ws;
  int4*  rectG = (int4*)(ws + QH_B);             // [6291456, 6324224)
  float* invG  = (float*)(ws + QH_B + 32768);    // [6324224, 6332416)
  float* lp0   = (float*)(ws + QH_B + 40960);    // [6332416, 6529024)
  float* lp1   = lp0 + 49152;                    // [6529024, 6725632) < WC_B
  // qh/kh/vh
  bf16* qh = (bf16*)(ws + WC_B);
  bf16* kh = (bf16*)(ws + WC_B + QH_B);
  bf16* vh = (bf16*)(ws + WC_B + 2 * QH_B);
  // Op1 aliases kh+vh (dead after k_area_pre); exactly 2*QH_B = 12582912 B
  float* Op1 = (float*)(ws + WC_B + QH_B);
  // pre-k_proj aliases into (not-yet-written) qh/kh region
  bf16* wqkvb = (bf16*)(ws + WC_B);
  bf16* wqT   = (bf16*)(ws + WC_B + 3538944);
  bf16* wkT   = (bf16*)(ws + WC_B + 4718592);
  bf16* wvT   = (bf16*)(ws + WC_B + 5898240);
  // PRIMARY: materialized pooled areas (dead after attn; woT aliases here)
  bf16* Karea  = (bf16*)(ws + WC_B + 3 * QH_B);
  bf16* VareaT = (bf16*)(ws + WC_B + 3 * QH_B + AREA_B);
  // FALLBACK: SAT buffers (r0 layout, known fit at 54,362,112)
  float* Ik = (float*)(ws + WC_B + 3 * QH_B);
  float* Iv = Ik + 3551232;
  bf16* woT = (bf16*)(ws + WC_B + 3 * QH_B);

  const size_t REQ = WC_B + 3 * QH_B + 2 * AREA_B;  // 126,615,552
  const bool primary = (ws_size >= REQ);

  k_prep<<<dim3(6536), 256, 0, stream>>>(x, wqkv, wq, wk, wv, xb, wqkvb,
                                         wqT, wkT, wvT, rectG, invG);
  k_combine_m<<<dim3(12, 12, 3), 256, 0, stream>>>(wqkvb, wqT, wkT, wvT, WcTb);
  k_proj_m<<<dim3(12, 32, 3), 256, 0, stream>>>(xb, WcTb, bq, bk, bv, qh, kh, vh);
  if (primary) {
    k_area_pre<<<dim3(384), 1024, 0, stream>>>(kh, vh, rectG, invG, Karea, VareaT);
    k_attn_g<<<dim3(192, 2, 2), 256, 0, stream>>>(qh, Karea, VareaT,
                                                  Op0, Op1, lp0, lp1);
    // norm + wo transpose-cast fused (woT aliases dead Karea region)
    k_norm2t<<<dim3(3648), 256, 0, stream>>>(Op0, Op1, lp0, lp1, attno, wo, woT);
  } else {
    k_integral_p<<<dim3(384), 1024, 0, stream>>>(kh, vh, Ik, Iv);
    k_attn_m<<<dim3(192), 1024, 0, stream>>>(qh, Ik, Iv, rectG, invG, attno);
    k_tcast1<<<dim3(24, 24), 256, 0, stream>>>(wo, woT);
  }
  k_out_m<<<dim3(12, 64), 256, 0, stream>>>(attno, woT, bo, out);
}

// Round 13
// 228.229 us; speedup vs baseline: 1.0085x; 1.0085x over previous
//
#include <hip/hip_runtime.h>
#include <hip/hip_bf16.h>

typedef __hip_bfloat16 bf16;
typedef __attribute__((ext_vector_type(8))) short short8b;
typedef __attribute__((ext_vector_type(4))) short short4b;
typedef __attribute__((ext_vector_type(4))) float f32x4;

#define NAREA 2025
#define NAREA_PAD 2048
#define L2E 1.4426950408889634f

static __device__ __forceinline__ float b2f(bf16 x) { return __bfloat162float(x); }
static __device__ __forceinline__ short f2bs(float f) {
  bf16 h = __float2bfloat16(f);
  return *(short*)&h;
}

// async global->LDS, 16B/lane; lds base must be wave-uniform (lane*16 added by HW)
static __device__ __forceinline__ void gll16(const void* g, void* l) {
  __builtin_amdgcn_global_load_lds(
      (const __attribute__((address_space(1))) unsigned int*)(unsigned long long)g,
      (__attribute__((address_space(3))) unsigned int*)(unsigned int)(unsigned long long)l,
      16, 0, 0);
}

// ---------------------------------------------------------------------------
// Fused prep: [0,4800) cast x+wqkv; [4800,6528) transpose-cast wq/wk/wv;
// [6528,6536) rect table.
// ---------------------------------------------------------------------------
__global__ __launch_bounds__(256) void k_prep(
    const float* __restrict__ x, const float* __restrict__ wqkv,
    const float* __restrict__ wq, const float* __restrict__ wk,
    const float* __restrict__ wv,
    bf16* __restrict__ xb, bf16* __restrict__ wqkvb,
    bf16* __restrict__ wqT, bf16* __restrict__ wkT, bf16* __restrict__ wvT,
    int4* __restrict__ rectG, float* __restrict__ invG)
{
  __shared__ float tile[32][33];
  int b = blockIdx.x;
  if (b < 4800) {
    int idx = (b * 256 + threadIdx.x) * 4;
    const int NX = 4096 * 768;
    float4 v;
    bf16* d;
    if (idx < NX) { v = *(const float4*)(x + idx); d = xb + idx; }
    else { v = *(const float4*)(wqkv + (idx - NX)); d = wqkvb + (idx - NX); }
    short4b s = {f2bs(v.x), f2bs(v.y), f2bs(v.z), f2bs(v.w)};
    *(short4b*)d = s;
    return;
  }
  if (b < 6528) {
    int r = b - 4800;
    int z = r / 576; r -= z * 576;
    int by = r / 24, bx = r - by * 24;
    const float* src = (z == 0) ? wq : (z == 1) ? wk : wv;
    bf16* dst = (z == 0) ? wqT : (z == 1) ? wkT : wvT;
    int r0 = by * 32, c0 = bx * 32;
    int lx = threadIdx.x & 31, ly = threadIdx.x >> 5;
#pragma unroll
    for (int yy = 0; yy < 4; ++yy)
      tile[ly + yy * 8][lx] = src[(size_t)(r0 + ly + yy * 8) * 768 + c0 + lx];
    __syncthreads();
#pragma unroll
    for (int yy = 0; yy < 4; ++yy)
      dst[(size_t)(c0 + ly + yy * 8) * 768 + r0 + lx] =
          __float2bfloat16(tile[lx][ly + yy * 8]);
    return;
  }
  int m = (b - 6528) * 256 + threadIdx.x;
  if (m >= NAREA_PAD) return;
  int4 rc = make_int4(0, 0, 0, 0);
  float iv = 0.f;
  if (m < NAREA) {
    int rem = m, ah = 1, aw = 1, found = 0;
    for (int a = 1; a <= 3 && !found; ++a)
      for (int w = 1; w <= 3 && !found; ++w) {
        int np = (17 - a) * (17 - w);
        if (rem < np) { ah = a; aw = w; found = 1; }
        else rem -= np;
      }
    int cw = 17 - aw;
    int y = rem / cw, xx = rem - y * cw;
    rc.x = (y * 17 + xx) * 64;
    rc.y = (y * 17 + (xx + aw)) * 64;
    rc.z = ((y + ah) * 17 + xx) * 64;
    rc.w = ((y + ah) * 17 + (xx + aw)) * 64;
    iv = 1.0f / (float)(ah * aw);
  }
  rectG[m] = rc;
  invG[m] = iv;
}

// ---------------------------------------------------------------------------
// Transpose-cast 768x768 fp32 -> bf16 (fallback path only; primary folds
// this into k_norm2t).
// ---------------------------------------------------------------------------
__global__ __launch_bounds__(256) void k_tcast1(
    const float* __restrict__ src, bf16* __restrict__ dst)
{
  __shared__ float tile[32][33];
  int r0 = blockIdx.y * 32, c0 = blockIdx.x * 32;
  int lx = threadIdx.x & 31, ly = threadIdx.x >> 5;
#pragma unroll
  for (int yy = 0; yy < 4; ++yy)
    tile[ly + yy * 8][lx] = src[(size_t)(r0 + ly + yy * 8) * 768 + c0 + lx];
  __syncthreads();
#pragma unroll
  for (int yy = 0; yy < 4; ++yy)
    dst[(size_t)(c0 + ly + yy * 8) * 768 + r0 + lx] =
        __float2bfloat16(tile[lx][ly + yy * 8]);
}

// ===========================================================================
// MFMA GEMM cores (m97 staging pattern). Tiles per r9 (r12's operand swap
// reverted: store-instruction reduction was null, swap cost ~4us net):
//   k_combine_m: 64x64  -> grid (12,12,3) = 432 blocks
//   k_proj_m:    128x64 -> grid (12,32,3) = 1152 blocks
//   k_out_m:     64x64  -> grid (12,64)   = 768 blocks
// ===========================================================================

// Wc^T[t][n][m] (bf16) = (wqkv[:,t] @ w_{q,k,v})^T ; 64x64 tile
__global__ __launch_bounds__(256) void k_combine_m(
    const bf16* __restrict__ wqkvb, const bf16* __restrict__ wqT,
    const bf16* __restrict__ wkT, const bf16* __restrict__ wvT,
    bf16* __restrict__ WcTb)
{
  __shared__ __align__(16) short As[2][64 * 32];
  __shared__ __align__(16) short Bs[2][64 * 32];
  const int t3 = blockIdx.z;
  const bf16* BT = (t3 == 0) ? wqT : (t3 == 1) ? wkT : wvT;
  const int m0 = blockIdx.y * 64, n0 = blockIdx.x * 64;
  const int tid = threadIdx.x, lane = tid & 63, w = tid >> 6;
  const int tt = lane & 15, q4 = lane >> 4;
  const int moff = (w & 1) * 32, noff = (w >> 1) * 32;
  const int r_a = tid >> 2, kc = (tid & 3) * 8;

  f32x4 acc[2][2];
#pragma unroll
  for (int i = 0; i < 2; ++i)
#pragma unroll
    for (int j = 0; j < 2; ++j) acc[i][j] = (f32x4){0.f, 0.f, 0.f, 0.f};

#define STAGE_C(k0, buf)                                                        \
  {                                                                             \
    gll16(wqkvb + (size_t)(m0 + r_a) * 2304 + t3 * 768 + (k0) + kc,             \
          &As[buf][w * 512]);                                                   \
    gll16(BT + (size_t)(n0 + r_a) * 768 + (k0) + kc, &Bs[buf][w * 512]);        \
  }

  STAGE_C(0, 0);
  for (int it = 0; it < 24; ++it) {
    __syncthreads();
    if (it < 23) STAGE_C((it + 1) * 32, (it + 1) & 1);
    const short* as = As[it & 1];
    const short* bs = Bs[it & 1];
    short8b afr[2], bfr[2];
#pragma unroll
    for (int mt = 0; mt < 2; ++mt)
      afr[mt] = *(const short8b*)&as[(moff + mt * 16 + tt) * 32 + q4 * 8];
#pragma unroll
    for (int nt = 0; nt < 2; ++nt)
      bfr[nt] = *(const short8b*)&bs[(noff + nt * 16 + tt) * 32 + q4 * 8];
#pragma unroll
    for (int mt = 0; mt < 2; ++mt)
#pragma unroll
      for (int nt = 0; nt < 2; ++nt)
        acc[mt][nt] = __builtin_amdgcn_mfma_f32_16x16x32_bf16(afr[mt], bfr[nt], acc[mt][nt], 0, 0, 0);
  }
#undef STAGE_C

  bf16* C = WcTb + (size_t)t3 * 768 * 768;
#pragma unroll
  for (int nt = 0; nt < 2; ++nt) {
    int n = n0 + noff + nt * 16 + tt;
#pragma unroll
    for (int mt = 0; mt < 2; ++mt) {
      int mb = m0 + moff + mt * 16 + q4 * 4;
      short4b v = {f2bs(acc[mt][nt][0]), f2bs(acc[mt][nt][1]),
                   f2bs(acc[mt][nt][2]), f2bs(acc[mt][nt][3])};
      *(short4b*)&C[(size_t)n * 768 + mb] = v;
    }
  }
}

// qh/kh/vh = xb @ Wc[t] + bias, scattered to [(b*12+h)][n][d] bf16 ; 128x64
__global__ __launch_bounds__(256) void k_proj_m(
    const bf16* __restrict__ xb, const bf16* __restrict__ WcTb,
    const float* __restrict__ bq, const float* __restrict__ bk,
    const float* __restrict__ bv,
    bf16* __restrict__ qh, bf16* __restrict__ kh, bf16* __restrict__ vh)
{
  __shared__ __align__(16) short As[2][128 * 32];
  __shared__ __align__(16) short Bs[2][64 * 32];
  const int t3 = blockIdx.z;
  const bf16* BT = WcTb + (size_t)t3 * 768 * 768;
  const float* bias = (t3 == 0) ? bq : (t3 == 1) ? bk : bv;
  bf16* dst = (t3 == 0) ? qh : (t3 == 1) ? kh : vh;
  const int m0 = blockIdx.y * 128, n0 = blockIdx.x * 64;
  const int tid = threadIdx.x, lane = tid & 63, w = tid >> 6;
  const int tt = lane & 15, q4 = lane >> 4;
  const int moff = (w & 1) * 64, noff = (w >> 1) * 32;
  const int r_a = tid >> 2, kc = (tid & 3) * 8;

  f32x4 acc[4][2];
#pragma unroll
  for (int i = 0; i < 4; ++i)
#pragma unroll
    for (int j = 0; j < 2; ++j) acc[i][j] = (f32x4){0.f, 0.f, 0.f, 0.f};

#define STAGE_P(k0, buf)                                                        \
  {                                                                             \
    gll16(xb + (size_t)(m0 + r_a) * 768 + (k0) + kc, &As[buf][w * 512]);        \
    gll16(xb + (size_t)(m0 + r_a + 64) * 768 + (k0) + kc,                       \
          &As[buf][2048 + w * 512]);                                            \
    gll16(BT + (size_t)(n0 + r_a) * 768 + (k0) + kc, &Bs[buf][w * 512]);        \
  }

  STAGE_P(0, 0);
  for (int it = 0; it < 24; ++it) {
    __syncthreads();
    if (it < 23) STAGE_P((it + 1) * 32, (it + 1) & 1);
    const short* as = As[it & 1];
    const short* bs = Bs[it & 1];
    short8b afr[4], bfr[2];
#pragma unroll
    for (int mt = 0; mt < 4; ++mt)
      afr[mt] = *(const short8b*)&as[(moff + mt * 16 + tt) * 32 + q4 * 8];
#pragma unroll
    for (int nt = 0; nt < 2; ++nt)
      bfr[nt] = *(const short8b*)&bs[(noff + nt * 16 + tt) * 32 + q4 * 8];
#pragma unroll
    for (int mt = 0; mt < 4; ++mt)
#pragma unroll
      for (int nt = 0; nt < 2; ++nt)
        acc[mt][nt] = __builtin_amdgcn_mfma_f32_16x16x32_bf16(afr[mt], bfr[nt], acc[mt][nt], 0, 0, 0);
  }
#undef STAGE_P

#pragma unroll
  for (int nt = 0; nt < 2; ++nt) {
    int c = n0 + noff + nt * 16 + tt;
    float bvv = bias[c];
    int h = c >> 6, d = c & 63;
#pragma unroll
    for (int mt = 0; mt < 4; ++mt) {
#pragma unroll
      for (int r = 0; r < 4; ++r) {
        int m = m0 + moff + mt * 16 + q4 * 4 + r;
        dst[(((size_t)((m >> 8) * 12 + h)) << 14) + ((m & 255) << 6) + d] =
            __float2bfloat16(acc[mt][nt][r] + bvv);
      }
    }
  }
}

// out = gather(attno) @ wo + bo (fp32 out) ; 64x64 tile
__global__ __launch_bounds__(256) void k_out_m(
    const bf16* __restrict__ attno, const bf16* __restrict__ woT,
    const float* __restrict__ bo, float* __restrict__ out)
{
  __shared__ __align__(16) short As[2][64 * 32];
  __shared__ __align__(16) short Bs[2][64 * 32];
  const int m0 = blockIdx.y * 64, n0 = blockIdx.x * 64;
  const int tid = threadIdx.x, lane = tid & 63, w = tid >> 6;
  const int tt = lane & 15, q4 = lane >> 4;
  const int moff = (w & 1) * 32, noff = (w >> 1) * 32;
  const int r_a = tid >> 2, kc = (tid & 3) * 8;
  const int m_a0 = m0 + r_a;

  f32x4 acc[2][2];
#pragma unroll
  for (int i = 0; i < 2; ++i)
#pragma unroll
    for (int j = 0; j < 2; ++j) acc[i][j] = (f32x4){0.f, 0.f, 0.f, 0.f};

#define STAGE_O(k0, buf)                                                        \
  {                                                                             \
    int k = (k0) + kc;                                                          \
    gll16(attno + (((size_t)((m_a0 >> 8) * 12 + (k >> 6))) << 14) +             \
              ((m_a0 & 255) << 6) + (k & 63),                                   \
          &As[buf][w * 512]);                                                   \
    gll16(woT + (size_t)(n0 + r_a) * 768 + k, &Bs[buf][w * 512]);               \
  }

  STAGE_O(0, 0);
  for (int it = 0; it < 24; ++it) {
    __syncthreads();
    if (it < 23) STAGE_O((it + 1) * 32, (it + 1) & 1);
    const short* as = As[it & 1];
    const short* bs = Bs[it & 1];
    short8b afr[2], bfr[2];
#pragma unroll
    for (int mt = 0; mt < 2; ++mt)
      afr[mt] = *(const short8b*)&as[(moff + mt * 16 + tt) * 32 + q4 * 8];
#pragma unroll
    for (int nt = 0; nt < 2; ++nt)
      bfr[nt] = *(const short8b*)&bs[(noff + nt * 16 + tt) * 32 + q4 * 8];
#pragma unroll
    for (int mt = 0; mt < 2; ++mt)
#pragma unroll
      for (int nt = 0; nt < 2; ++nt)
        acc[mt][nt] = __builtin_amdgcn_mfma_f32_16x16x32_bf16(afr[mt], bfr[nt], acc[mt][nt], 0, 0, 0);
  }
#undef STAGE_O

#pragma unroll
  for (int nt = 0; nt < 2; ++nt) {
    int c = n0 + noff + nt * 16 + tt;
    float bvv = bo[c];
#pragma unroll
    for (int mt = 0; mt < 2; ++mt)
#pragma unroll
      for (int r = 0; r < 4; ++r) {
        int m = m0 + moff + mt * 16 + q4 * 4 + r;
        out[(size_t)m * 768 + c] = acc[mt][nt][r] + bvv;
      }
  }
}

// ---------------------------------------------------------------------------
// PRIMARY path: SAT in LDS + materialize pooled areas.
// K-pass band-sliding with log2e FOLDED into the mean constants (Karea
// holds k_mean * log2e so attention uses raw v_exp_f32 = 2^x directly).
// V-pass: it-outer loop hoists the rectG load + corner rescale (r10).
// ---------------------------------------------------------------------------
__global__ __launch_bounds__(1024) void k_area_pre(
    const bf16* __restrict__ kh, const bf16* __restrict__ vh,
    const int4* __restrict__ rectG, const float* __restrict__ invG,
    bf16* __restrict__ Karea, bf16* __restrict__ VareaT)
{
  __shared__ float sat[17 * 17 * 65];
  int bh = blockIdx.x >> 1;
  bool isv = blockIdx.x & 1;
  const bf16* src = (isv ? vh : kh) + ((size_t)bh << 14);
  int tid = threadIdx.x;
  int d = tid & 63;
  int row = tid >> 6;
  {
    float run = 0.f;
    sat[((row + 1) * 17) * 65 + d] = 0.f;
#pragma unroll
    for (int xx = 0; xx < 16; ++xx) {
      run += b2f(src[(row * 16 + xx) * 64 + d]);
      sat[((row + 1) * 17 + (xx + 1)) * 65 + d] = run;
    }
    if (row == 0) {
#pragma unroll
      for (int xx = 0; xx < 17; ++xx) sat[xx * 65 + d] = 0.f;
    }
  }
  __syncthreads();
  {
    int x = row + 1;
    float run = 0.f;
#pragma unroll
    for (int y = 1; y <= 16; ++y) {
      run += sat[(y * 17 + x) * 65 + d];
      sat[(y * 17 + x) * 65 + d] = run;
    }
  }
  __syncthreads();
  if (!isv) {
    // K band-sliding: wave = (y,ah) combo (45 total), lane = d.
    bf16* out = Karea + ((size_t)bh << 17);   // bh*2048*64
    for (int c = row; c < 45; c += 16) {
      int ah, y;
      if (c < 16)      { ah = 1; y = c; }
      else if (c < 31) { ah = 2; y = c - 16; }
      else             { ah = 3; y = c - 31; }
      int b1, b2, b3;
      if (ah == 1)      { b1 = 0;    b2 = 256;  b3 = 496;  }
      else if (ah == 2) { b1 = 720;  b2 = 960;  b3 = 1185; }
      else              { b1 = 1395; b2 = 1619; b3 = 1829; }
      float V[17];
#pragma unroll
      for (int x = 0; x < 17; ++x)
        V[x] = sat[((y + ah) * 17 + x) * 65 + d] - sat[(y * 17 + x) * 65 + d];
      {
        int b = b1 + y * 16;
        float iv = L2E / (float)ah;
#pragma unroll
        for (int x = 0; x < 16; ++x)
          out[(size_t)(b + x) * 64 + d] = __float2bfloat16((V[x + 1] - V[x]) * iv);
      }
      {
        int b = b2 + y * 15;
        float iv = L2E / (float)(2 * ah);
#pragma unroll
        for (int x = 0; x < 15; ++x)
          out[(size_t)(b + x) * 64 + d] = __float2bfloat16((V[x + 2] - V[x]) * iv);
      }
      {
        int b = b3 + y * 14;
        float iv = L2E / (float)(3 * ah);
#pragma unroll
        for (int x = 0; x < 14; ++x)
          out[(size_t)(b + x) * 64 + d] = __float2bfloat16((V[x + 3] - V[x]) * iv);
      }
    }
    if (row == 15) {
      for (int m = NAREA; m < NAREA_PAD; ++m)
        out[(size_t)m * 64 + d] = __float2bfloat16(0.f);
    }
  } else {
    // V: sum-pooled, transposed [it][d][m]; lanes span m -> coalesced 2B
    // stores. it-outer: one rectG load + corner rescale per (it,mcol).
    int mcol = tid & 63;
    int r16 = tid >> 6;             // 0..15
    bf16* out = VareaT + ((size_t)bh << 17);
    for (int it = 0; it < 32; ++it) {
      int4 rc = rectG[it * 64 + mcol];
      int cx = rc.x + (rc.x >> 6), cy = rc.y + (rc.y >> 6);
      int cz = rc.z + (rc.z >> 6), cw = rc.w + (rc.w >> 6);
#pragma unroll
      for (int j = 0; j < 4; ++j) {
        int dd = r16 + j * 16;
        float df = sat[cw + dd] - sat[cy + dd] - sat[cz + dd] + sat[cx + dd];
        out[(((size_t)it << 6) + dd) * 64 + mcol] = __float2bfloat16(df);
      }
    }
  }
}

// ---------------------------------------------------------------------------
// PRIMARY attention (r11-verified): 256-thr / 4-wave, 32 q/wave, area-split
// 2x, grid (192,2,2) = 768 blocks = 3/CU, additive partials.
// p = v_exp_f32(s) directly (one instr; log2e pre-folded into Karea).
// ---------------------------------------------------------------------------
__global__ __launch_bounds__(256, 4) void k_attn_g(
    const bf16* __restrict__ qh, const bf16* __restrict__ Karea,
    const bf16* __restrict__ VareaT,
    float* __restrict__ Op0, float* __restrict__ Op1,
    float* __restrict__ lp0, float* __restrict__ lp1)
{
  __shared__ __align__(16) short aK2[2][64 * 80];
  __shared__ __align__(16) short aVt2[2][64 * 80];

  const int tid = threadIdx.x;
  const int w = tid >> 6;            // 0..3
  const int lane = tid & 63;
  const int t = lane & 15;
  const int q4 = lane >> 4;
  const int bh = blockIdx.x;
  const int Q0 = blockIdx.y * 128;
  const int it0 = blockIdx.z * 16;   // area half: tiles [it0, it0+16)
  const int rbase = (t & 12) * 2 + (t & 3);

  const bf16* Kb = Karea + ((size_t)bh << 17);
  const bf16* Vb = VareaT + ((size_t)bh << 17);
  const bf16* qrowA = qh + ((size_t)bh << 14) + (size_t)(Q0 + w * 32 + t) * 64;
  const bf16* qrowB = qrowA + 16 * 64;

  short8b qfA0 = *(const short8b*)(qrowA + q4 * 8);
  short8b qfA1 = *(const short8b*)(qrowA + 32 + q4 * 8);
  short8b qfB0 = *(const short8b*)(qrowB + q4 * 8);
  short8b qfB1 = *(const short8b*)(qrowB + 32 + q4 * 8);

  f32x4 OA[4], OB[4];
#pragma unroll
  for (int i = 0; i < 4; ++i) {
    OA[i] = (f32x4){0.f, 0.f, 0.f, 0.f};
    OB[i] = (f32x4){0.f, 0.f, 0.f, 0.f};
  }
  float lA = 0.f, lB = 0.f;

  const int a8 = tid >> 2;           // 0..63: area slot (K) / d row (V)
  const int c8 = (tid & 3) * 16;     // col start (elements); each thr 2x8

  {
    size_t off = ((size_t)(it0 * 64 + a8) << 6) + c8;
    short8b k0a = *(const short8b*)&Kb[off];
    short8b k0b = *(const short8b*)&Kb[off + 8];
    short8b v0a = *(const short8b*)&Vb[off];
    short8b v0b = *(const short8b*)&Vb[off + 8];
    *(short8b*)&aK2[0][a8 * 80 + c8] = k0a;
    *(short8b*)&aK2[0][a8 * 80 + c8 + 8] = k0b;
    *(short8b*)&aVt2[0][a8 * 80 + c8] = v0a;
    *(short8b*)&aVt2[0][a8 * 80 + c8 + 8] = v0b;
  }

  for (int it = it0; it < it0 + 16; ++it) {
    short8b kna, knb, vna, vnb;
    if (it + 1 < it0 + 16) {
      size_t off = ((size_t)((it + 1) * 64 + a8) << 6) + c8;
      kna = *(const short8b*)&Kb[off];
      knb = *(const short8b*)&Kb[off + 8];
      vna = *(const short8b*)&Vb[off];
      vnb = *(const short8b*)&Vb[off + 8];
    }
    __syncthreads();
    const short* aK = aK2[it & 1];
    const short* aVt = aVt2[it & 1];
    if (it + 1 < it0 + 16) {
      short* aKn = aK2[(it + 1) & 1];
      short* aVtn = aVt2[(it + 1) & 1];
      *(short8b*)&aKn[a8 * 80 + c8] = kna;
      *(short8b*)&aKn[a8 * 80 + c8 + 8] = knb;
      *(short8b*)&aVtn[a8 * 80 + c8] = vna;
      *(short8b*)&aVtn[a8 * 80 + c8 + 8] = vnb;
    }

    const int t0 = it * 64;
    const bool edge = (t0 + 64 > NAREA);
    union { short8b v; unsigned u[4]; } apvA[2], apvB[2];
#pragma unroll
    for (int at = 0; at < 4; ++at) {
      int row = rbase + (at & 1) * 4 + (at >> 1) * 32;
      short8b af0 = *(const short8b*)&aK[row * 80 + q4 * 8];
      short8b af1 = *(const short8b*)&aK[row * 80 + 32 + q4 * 8];
      int abase = t0 + (at >> 1) * 32 + q4 * 8 + (at & 1) * 4;
      {
        f32x4 s = (f32x4){0.f, 0.f, 0.f, 0.f};
        s = __builtin_amdgcn_mfma_f32_16x16x32_bf16(af0, qfA0, s, 0, 0, 0);
        s = __builtin_amdgcn_mfma_f32_16x16x32_bf16(af1, qfA1, s, 0, 0, 0);
        float p[4];
#pragma unroll
        for (int r = 0; r < 4; ++r) {
          p[r] = __builtin_amdgcn_exp2f(s[r]);
          if (edge && (abase + r >= NAREA)) p[r] = 0.f;
        }
        lA += (p[0] + p[1]) + (p[2] + p[3]);
        unsigned lo = ((unsigned)(unsigned short)f2bs(p[1]) << 16) |
                      (unsigned short)f2bs(p[0]);
        unsigned hi = ((unsigned)(unsigned short)f2bs(p[3]) << 16) |
                      (unsigned short)f2bs(p[2]);
        apvA[at >> 1].u[(at & 1) * 2 + 0] = lo;
        apvA[at >> 1].u[(at & 1) * 2 + 1] = hi;
      }
      {
        f32x4 s = (f32x4){0.f, 0.f, 0.f, 0.f};
        s = __builtin_amdgcn_mfma_f32_16x16x32_bf16(af0, qfB0, s, 0, 0, 0);
        s = __builtin_amdgcn_mfma_f32_16x16x32_bf16(af1, qfB1, s, 0, 0, 0);
        float p[4];
#pragma unroll
        for (int r = 0; r < 4; ++r) {
          p[r] = __builtin_amdgcn_exp2f(s[r]);
          if (edge && (abase + r >= NAREA)) p[r] = 0.f;
        }
        lB += (p[0] + p[1]) + (p[2] + p[3]);
        unsigned lo = ((unsigned)(unsigned short)f2bs(p[1]) << 16) |
                      (unsigned short)f2bs(p[0]);
        unsigned hi = ((unsigned)(unsigned short)f2bs(p[3]) << 16) |
                      (unsigned short)f2bs(p[2]);
        apvB[at >> 1].u[(at & 1) * 2 + 0] = lo;
        apvB[at >> 1].u[(at & 1) * 2 + 1] = hi;
      }
    }
#pragma unroll
    for (int nt = 0; nt < 4; ++nt) {
      short8b vf0 = *(const short8b*)&aVt[(nt * 16 + t) * 80 + q4 * 8];
      short8b vf1 = *(const short8b*)&aVt[(nt * 16 + t) * 80 + 32 + q4 * 8];
      OA[nt] = __builtin_amdgcn_mfma_f32_16x16x32_bf16(apvA[0].v, vf0, OA[nt], 0, 0, 0);
      OA[nt] = __builtin_amdgcn_mfma_f32_16x16x32_bf16(apvA[1].v, vf1, OA[nt], 0, 0, 0);
      OB[nt] = __builtin_amdgcn_mfma_f32_16x16x32_bf16(apvB[0].v, vf0, OB[nt], 0, 0, 0);
      OB[nt] = __builtin_amdgcn_mfma_f32_16x16x32_bf16(apvB[1].v, vf1, OB[nt], 0, 0, 0);
    }
  }

  lA += __shfl_xor(lA, 16, 64);
  lA += __shfl_xor(lA, 32, 64);
  lB += __shfl_xor(lB, 16, 64);
  lB += __shfl_xor(lB, 32, 64);

  float* lp = blockIdx.z ? lp1 : lp0;
  float* Op = blockIdx.z ? Op1 : Op0;
  if (q4 == 0) {
    lp[(bh << 8) + Q0 + w * 32 + t] = lA;
    lp[(bh << 8) + Q0 + w * 32 + 16 + t] = lB;
  }
  float* Ob = Op + (((size_t)(bh << 8) + Q0 + w * 32) << 6);
#pragma unroll
  for (int r = 0; r < 4; ++r) {
    int qr = q4 * 4 + r;
#pragma unroll
    for (int nt = 0; nt < 4; ++nt) {
      Ob[qr * 64 + nt * 16 + t] = OA[nt][r];
      Ob[(16 + qr) * 64 + nt * 16 + t] = OB[nt][r];
    }
  }
}

// ---------------------------------------------------------------------------
// Combine area-half partials + (folded) wo transpose-cast.
// blocks [0,3072): attno = (O0+O1)/(l0+l1); blocks [3072,3648): tcast wo.
// ---------------------------------------------------------------------------
__global__ __launch_bounds__(256) void k_norm2t(
    const float* __restrict__ Op0, const float* __restrict__ Op1,
    const float* __restrict__ lp0, const float* __restrict__ lp1,
    bf16* __restrict__ attno,
    const float* __restrict__ wo, bf16* __restrict__ woT)
{
  if (blockIdx.x < 3072) {
    int i = (blockIdx.x * 256 + threadIdx.x) * 4;
    f32x4 a = *(const f32x4*)(Op0 + i);
    f32x4 b = *(const f32x4*)(Op1 + i);
    int q = i >> 6;
    float invl = 1.0f / (lp0[q] + lp1[q]);
    short4b s = {f2bs((a[0] + b[0]) * invl), f2bs((a[1] + b[1]) * invl),
                 f2bs((a[2] + b[2]) * invl), f2bs((a[3] + b[3]) * invl)};
    *(short4b*)(attno + i) = s;
    return;
  }
  __shared__ float tile[32][33];
  int b = blockIdx.x - 3072;
  int bxx = b % 24, byy = b / 24;
  int r0 = byy * 32, c0 = bxx * 32;
  int lx = threadIdx.x & 31, ly = threadIdx.x >> 5;
#pragma unroll
  for (int yy = 0; yy < 4; ++yy)
    tile[ly + yy * 8][lx] = wo[(size_t)(r0 + ly + yy * 8) * 768 + c0 + lx];
  __syncthreads();
#pragma unroll
  for (int yy = 0; yy < 4; ++yy)
    woT[(size_t)(c0 + ly + yy * 8) * 768 + r0 + lx] =
        __float2bfloat16(tile[lx][ly + yy * 8]);
}

// ---------------------------------------------------------------------------
// FALLBACK path (ws too small for materialized areas): round-0 verbatim.
// ---------------------------------------------------------------------------
__global__ __launch_bounds__(1024) void k_integral_p(
    const bf16* __restrict__ kh, const bf16* __restrict__ vh,
    float* __restrict__ Ik, float* __restrict__ Iv)
{
  __shared__ float sat[17 * 17 * 64];
  int bh = blockIdx.x >> 1;
  bool isv = blockIdx.x & 1;
  const bf16* src = (isv ? vh : kh) + ((size_t)bh << 14);
  float* dst = (isv ? Iv : Ik) + (size_t)bh * 18496;
  int tid = threadIdx.x;
  int d = tid & 63;
  int row = tid >> 6;
  {
    float run = 0.f;
    sat[((row + 1) * 17) * 64 + d] = 0.f;
#pragma unroll
    for (int xx = 0; xx < 16; ++xx) {
      run += b2f(src[(row * 16 + xx) * 64 + d]);
      sat[((row + 1) * 17 + (xx + 1)) * 64 + d] = run;
    }
    if (row == 0) {
#pragma unroll
      for (int xx = 0; xx < 17; ++xx) sat[xx * 64 + d] = 0.f;
    }
  }
  __syncthreads();
  {
    int x = row + 1;
    float run = 0.f;
#pragma unroll
    for (int y = 1; y <= 16; ++y) {
      run += sat[(y * 17 + x) * 64 + d];
      sat[(y * 17 + x) * 64 + d] = run;
    }
  }
  __syncthreads();
  for (int i = tid; i < 18496; i += 1024) dst[i] = sat[i];
}

__global__ __launch_bounds__(1024) void k_attn_m(
    const bf16* __restrict__ qh, const float* __restrict__ Ik,
    const float* __restrict__ Iv, const int4* __restrict__ rectG,
    const float* __restrict__ invG, bf16* __restrict__ attno)
{
  __shared__ __align__(16) short aK2[2][64 * 80];
  __shared__ __align__(16) short aVt2[2][64 * 72];

  const int tid = threadIdx.x;
  const int lane = tid & 63;
  const int w = tid >> 6;
  const int t = lane & 15;
  const int q4 = lane >> 4;
  const int bh = blockIdx.x;
  const int rbase = (t & 12) * 2 + (t & 3);

  const float* Ikb = Ik + (size_t)bh * 18496;
  const float* Ivb = Iv + (size_t)bh * 18496;
  const bf16* qbase = qh + ((size_t)bh << 14);

  short8b qf0 = *(const short8b*)(qbase + (w * 16 + t) * 64 + q4 * 8);
  short8b qf1 = *(const short8b*)(qbase + (w * 16 + t) * 64 + 32 + q4 * 8);

  f32x4 O[4];
#pragma unroll
  for (int i = 0; i < 4; ++i) O[i] = (f32x4){0.f, 0.f, 0.f, 0.f};
  float l = 0.f;

  {
    short* aK = aK2[0];
    short* aVt = aVt2[0];
    short vp[4];
#pragma unroll
    for (int i = 0; i < 4; ++i) {
      int j = w * 4 + i;
      int4 rc = rectG[j];
      float iv = invG[j];
      float kc = Ikb[rc.w + lane] - Ikb[rc.y + lane] - Ikb[rc.z + lane] + Ikb[rc.x + lane];
      float vc = Ivb[rc.w + lane] - Ivb[rc.y + lane] - Ivb[rc.z + lane] + Ivb[rc.x + lane];
      aK[j * 80 + lane] = f2bs(kc * iv);
      vp[i] = f2bs(vc);
    }
    *(short4b*)&aVt[lane * 72 + w * 4] = (short4b){vp[0], vp[1], vp[2], vp[3]};
  }

  float kcr[4], vcr[4], ivr[4];
  for (int it = 0; it < 32; ++it) {
    if (it + 1 < 32) {
      int t0n = (it + 1) * 64;
#pragma unroll
      for (int i = 0; i < 4; ++i) {
        int j = t0n + w * 4 + i;
        int4 rc = rectG[j];
        ivr[i] = invG[j];
        kcr[i] = Ikb[rc.w + lane] - Ikb[rc.y + lane] - Ikb[rc.z + lane] + Ikb[rc.x + lane];
        vcr[i] = Ivb[rc.w + lane] - Ivb[rc.y + lane] - Ivb[rc.z + lane] + Ivb[rc.x + lane];
      }
    }
    __syncthreads();
    const short* aK = aK2[it & 1];
    const short* aVt = aVt2[it & 1];
    if (it + 1 < 32) {
      short* aKn = aK2[(it + 1) & 1];
      short* aVtn = aVt2[(it + 1) & 1];
      short vp[4];
#pragma unroll
      for (int i = 0; i < 4; ++i) {
        aKn[(w * 4 + i) * 80 + lane] = f2bs(kcr[i] * ivr[i]);
        vp[i] = f2bs(vcr[i]);
      }
      *(short4b*)&aVtn[lane * 72 + w * 4] = (short4b){vp[0], vp[1], vp[2], vp[3]};
    }

    const int t0 = it * 64;
    const bool edge = (t0 + 64 > NAREA);
    union { short8b v; unsigned u[4]; } apv[2];
#pragma unroll
    for (int at = 0; at < 4; ++at) {
      int row = rbase + (at & 1) * 4 + (at >> 1) * 32;
      short8b af0 = *(const short8b*)&aK[row * 80 + q4 * 8];
      short8b af1 = *(const short8b*)&aK[row * 80 + 32 + q4 * 8];
      f32x4 s = (f32x4){0.f, 0.f, 0.f, 0.f};
      s = __builtin_amdgcn_mfma_f32_16x16x32_bf16(af0, qf0, s, 0, 0, 0);
      s = __builtin_amdgcn_mfma_f32_16x16x32_bf16(af1, qf1, s, 0, 0, 0);
      int abase = t0 + (at >> 1) * 32 + q4 * 8 + (at & 1) * 4;
      float p[4];
#pragma unroll
      for (int r = 0; r < 4; ++r) {
        p[r] = __expf(s[r]);
        if (edge && (abase + r >= NAREA)) p[r] = 0.f;
      }
      l += (p[0] + p[1]) + (p[2] + p[3]);
      unsigned lo = ((unsigned)(unsigned short)f2bs(p[1]) << 16) |
                    (unsigned short)f2bs(p[0]);
      unsigned hi = ((unsigned)(unsigned short)f2bs(p[3]) << 16) |
                    (unsigned short)f2bs(p[2]);
      apv[at >> 1].u[(at & 1) * 2 + 0] = lo;
      apv[at >> 1].u[(at & 1) * 2 + 1] = hi;
    }
#pragma unroll
    for (int nt = 0; nt < 4; ++nt) {
      short8b vf0 = *(const short8b*)&aVt[(nt * 16 + t) * 72 + q4 * 8];
      short8b vf1 = *(const short8b*)&aVt[(nt * 16 + t) * 72 + 32 + q4 * 8];
      O[nt] = __builtin_amdgcn_mfma_f32_16x16x32_bf16(apv[0].v, vf0, O[nt], 0, 0, 0);
      O[nt] = __builtin_amdgcn_mfma_f32_16x16x32_bf16(apv[1].v, vf1, O[nt], 0, 0, 0);
    }
  }

  l += __shfl_xor(l, 16, 64);
  l += __shfl_xor(l, 32, 64);

  bf16* ob = attno + ((size_t)bh << 14);
#pragma unroll
  for (int r = 0; r < 4; ++r) {
    int qrow = q4 * 4 + r;
    float invl = 1.0f / __shfl(l, qrow, 64);
#pragma unroll
    for (int nt = 0; nt < 4; ++nt)
      ob[(w * 16 + qrow) * 64 + nt * 16 + t] = __float2bfloat16(O[nt][r] * invl);
  }
}

extern "C" void kernel_launch(void* const* d_in, const int* in_sizes, int n_in,
                              void* d_out, int out_size, void* d_ws, size_t ws_size,
                              hipStream_t stream) {
  const float* x    = (const float*)d_in[0];
  const float* wqkv = (const float*)d_in[1];
  const float* wq   = (const float*)d_in[2];
  const float* bq   = (const float*)d_in[3];
  const float* wk   = (const float*)d_in[4];
  const float* bk   = (const float*)d_in[5];
  const float* wv   = (const float*)d_in[6];
  const float* bv   = (const float*)d_in[7];
  const float* wo   = (const float*)d_in[8];
  const float* bo   = (const float*)d_in[9];
  float* out = (float*)d_out;

  char* ws = (char*)d_ws;
  char* ob = (char*)d_out;
  const size_t WC_B = 7077888;   // zone A size
  const size_t QH_B = 6291456;   // bf16 [192][256][64]
  const size_t AREA_B = 50331648; // bf16 [192][2048][64]

  // d_out as scratch: xb + WcTb (dead after k_proj_m), then Op0 (f32 attn
  // partial, = out_size), consumed by k_norm2t before k_out_m writes out.
  bf16* xb    = (bf16*)ob;                  // [0, 6291456)
  bf16* WcTb  = (bf16*)(ob + QH_B);         // [6291456, 9830400)
  float* Op0  = (float*)ob;                 // full 12582912 B
  // ws zone A: attno [0,6291456), rectG/invG, lp0/lp1
  bf16* attno = (bf16*)ws;
  int4*  rectG = (int4*)(ws + QH_B);             // [6291456, 6324224)
  float* invG  = (float*)(ws + QH_B + 32768);    // [6324224, 6332416)
  float* lp0   = (float*)(ws + QH_B + 40960);    // [6332416, 6529024)
  float* lp1   = lp0 + 49152;                    // [6529024, 6725632) < WC_B
  // qh/kh/vh
  bf16* qh = (bf16*)(ws + WC_B);
  bf16* kh = (bf16*)(ws + WC_B + QH_B);
  bf16* vh = (bf16*)(ws + WC_B + 2 * QH_B);
  // Op1 aliases kh+vh (dead after k_area_pre); exactly 2*QH_B = 12582912 B
  float* Op1 = (float*)(ws + WC_B + QH_B);
  // pre-k_proj aliases into (not-yet-written) qh/kh region
  bf16* wqkvb = (bf16*)(ws + WC_B);
  bf16* wqT   = (bf16*)(ws + WC_B + 3538944);
  bf16* wkT   = (bf16*)(ws + WC_B + 4718592);
  bf16* wvT   = (bf16*)(ws + WC_B + 5898240);
  // PRIMARY: materialized pooled areas (dead after attn; woT aliases here)
  bf16* Karea  = (bf16*)(ws + WC_B + 3 * QH_B);
  bf16* VareaT = (bf16*)(ws + WC_B + 3 * QH_B + AREA_B);
  // FALLBACK: SAT buffers (r0 layout, known fit at 54,362,112)
  float* Ik = (float*)(ws + WC_B + 3 * QH_B);
  float* Iv = Ik + 3551232;
  bf16* woT = (bf16*)(ws + WC_B + 3 * QH_B);

  const size_t REQ = WC_B + 3 * QH_B + 2 * AREA_B;  // 126,615,552
  const bool primary = (ws_size >= REQ);

  k_prep<<<dim3(6536), 256, 0, stream>>>(x, wqkv, wq, wk, wv, xb, wqkvb,
                                         wqT, wkT, wvT, rectG, invG);
  k_combine_m<<<dim3(12, 12, 3), 256, 0, stream>>>(wqkvb, wqT, wkT, wvT, WcTb);
  k_proj_m<<<dim3(12, 32, 3), 256, 0, stream>>>(xb, WcTb, bq, bk, bv, qh, kh, vh);
  if (primary) {
    k_area_pre<<<dim3(384), 1024, 0, stream>>>(kh, vh, rectG, invG, Karea, VareaT);
    k_attn_g<<<dim3(192, 2, 2), 256, 0, stream>>>(qh, Karea, VareaT,
                                                  Op0, Op1, lp0, lp1);
    // norm + wo transpose-cast fused (woT aliases dead Karea region)
    k_norm2t<<<dim3(3648), 256, 0, stream>>>(Op0, Op1, lp0, lp1, attno, wo, woT);
  } else {
    k_integral_p<<<dim3(384), 1024, 0, stream>>>(kh, vh, Ik, Iv);
    k_attn_m<<<dim3(192), 1024, 0, stream>>>(qh, Ik, Iv, rectG, invG, attno);
    k_tcast1<<<dim3(24, 24), 256, 0, stream>>>(wo, woT);
  }
  k_out_m<<<dim3(12, 64), 256, 0, stream>>>(attno, woT, bo, out);
}

// Round 14
// 222.173 us; speedup vs baseline: 1.0360x; 1.0273x over previous
//
#include <hip/hip_runtime.h>
#include <hip/hip_bf16.h>

typedef __hip_bfloat16 bf16;
typedef __attribute__((ext_vector_type(8))) short short8b;
typedef __attribute__((ext_vector_type(4))) short short4b;
typedef __attribute__((ext_vector_type(4))) float f32x4;

#define NAREA 2025
#define NAREA_PAD 2048
#define L2E 1.4426950408889634f

static __device__ __forceinline__ float b2f(bf16 x) { return __bfloat162float(x); }
static __device__ __forceinline__ short f2bs(float f) {
  bf16 h = __float2bfloat16(f);
  return *(short*)&h;
}

// async global->LDS, 16B/lane; lds base must be wave-uniform (lane*16 added by HW)
static __device__ __forceinline__ void gll16(const void* g, void* l) {
  __builtin_amdgcn_global_load_lds(
      (const __attribute__((address_space(1))) unsigned int*)(unsigned long long)g,
      (__attribute__((address_space(3))) unsigned int*)(unsigned int)(unsigned long long)l,
      16, 0, 0);
}

// ---------------------------------------------------------------------------
// Fused prep: [0,4800) cast x+wqkv; [4800,6528) transpose-cast wq/wk/wv;
// [6528,6536) rect table.
// ---------------------------------------------------------------------------
__global__ __launch_bounds__(256) void k_prep(
    const float* __restrict__ x, const float* __restrict__ wqkv,
    const float* __restrict__ wq, const float* __restrict__ wk,
    const float* __restrict__ wv,
    bf16* __restrict__ xb, bf16* __restrict__ wqkvb,
    bf16* __restrict__ wqT, bf16* __restrict__ wkT, bf16* __restrict__ wvT,
    int4* __restrict__ rectG, float* __restrict__ invG)
{
  __shared__ float tile[32][33];
  int b = blockIdx.x;
  if (b < 4800) {
    int idx = (b * 256 + threadIdx.x) * 4;
    const int NX = 4096 * 768;
    float4 v;
    bf16* d;
    if (idx < NX) { v = *(const float4*)(x + idx); d = xb + idx; }
    else { v = *(const float4*)(wqkv + (idx - NX)); d = wqkvb + (idx - NX); }
    short4b s = {f2bs(v.x), f2bs(v.y), f2bs(v.z), f2bs(v.w)};
    *(short4b*)d = s;
    return;
  }
  if (b < 6528) {
    int r = b - 4800;
    int z = r / 576; r -= z * 576;
    int by = r / 24, bx = r - by * 24;
    const float* src = (z == 0) ? wq : (z == 1) ? wk : wv;
    bf16* dst = (z == 0) ? wqT : (z == 1) ? wkT : wvT;
    int r0 = by * 32, c0 = bx * 32;
    int lx = threadIdx.x & 31, ly = threadIdx.x >> 5;
#pragma unroll
    for (int yy = 0; yy < 4; ++yy)
      tile[ly + yy * 8][lx] = src[(size_t)(r0 + ly + yy * 8) * 768 + c0 + lx];
    __syncthreads();
#pragma unroll
    for (int yy = 0; yy < 4; ++yy)
      dst[(size_t)(c0 + ly + yy * 8) * 768 + r0 + lx] =
          __float2bfloat16(tile[lx][ly + yy * 8]);
    return;
  }
  int m = (b - 6528) * 256 + threadIdx.x;
  if (m >= NAREA_PAD) return;
  int4 rc = make_int4(0, 0, 0, 0);
  float iv = 0.f;
  if (m < NAREA) {
    int rem = m, ah = 1, aw = 1, found = 0;
    for (int a = 1; a <= 3 && !found; ++a)
      for (int w = 1; w <= 3 && !found; ++w) {
        int np = (17 - a) * (17 - w);
        if (rem < np) { ah = a; aw = w; found = 1; }
        else rem -= np;
      }
    int cw = 17 - aw;
    int y = rem / cw, xx = rem - y * cw;
    rc.x = (y * 17 + xx) * 64;
    rc.y = (y * 17 + (xx + aw)) * 64;
    rc.z = ((y + ah) * 17 + xx) * 64;
    rc.w = ((y + ah) * 17 + (xx + aw)) * 64;
    iv = 1.0f / (float)(ah * aw);
  }
  rectG[m] = rc;
  invG[m] = iv;
}

// ---------------------------------------------------------------------------
// Transpose-cast 768x768 fp32 -> bf16 (fallback path only; primary folds
// this into k_norm2t).
// ---------------------------------------------------------------------------
__global__ __launch_bounds__(256) void k_tcast1(
    const float* __restrict__ src, bf16* __restrict__ dst)
{
  __shared__ float tile[32][33];
  int r0 = blockIdx.y * 32, c0 = blockIdx.x * 32;
  int lx = threadIdx.x & 31, ly = threadIdx.x >> 5;
#pragma unroll
  for (int yy = 0; yy < 4; ++yy)
    tile[ly + yy * 8][lx] = src[(size_t)(r0 + ly + yy * 8) * 768 + c0 + lx];
  __syncthreads();
#pragma unroll
  for (int yy = 0; yy < 4; ++yy)
    dst[(size_t)(c0 + ly + yy * 8) * 768 + r0 + lx] =
        __float2bfloat16(tile[lx][ly + yy * 8]);
}

// ===========================================================================
// MFMA GEMM cores (m97 staging pattern). Tiles per r9:
//   k_combine_m: 64x64  -> grid (12,12,3) = 432 blocks
//   k_proj_m:    128x64 -> grid (12,32,3) = 1152 blocks
//   k_out_m:     64x64  -> grid (12,64)   = 768 blocks
// ===========================================================================

// Wc^T[t][n][m] (bf16) = (wqkv[:,t] @ w_{q,k,v})^T ; 64x64 tile
__global__ __launch_bounds__(256) void k_combine_m(
    const bf16* __restrict__ wqkvb, const bf16* __restrict__ wqT,
    const bf16* __restrict__ wkT, const bf16* __restrict__ wvT,
    bf16* __restrict__ WcTb)
{
  __shared__ __align__(16) short As[2][64 * 32];
  __shared__ __align__(16) short Bs[2][64 * 32];
  const int t3 = blockIdx.z;
  const bf16* BT = (t3 == 0) ? wqT : (t3 == 1) ? wkT : wvT;
  const int m0 = blockIdx.y * 64, n0 = blockIdx.x * 64;
  const int tid = threadIdx.x, lane = tid & 63, w = tid >> 6;
  const int tt = lane & 15, q4 = lane >> 4;
  const int moff = (w & 1) * 32, noff = (w >> 1) * 32;
  const int r_a = tid >> 2, kc = (tid & 3) * 8;

  f32x4 acc[2][2];
#pragma unroll
  for (int i = 0; i < 2; ++i)
#pragma unroll
    for (int j = 0; j < 2; ++j) acc[i][j] = (f32x4){0.f, 0.f, 0.f, 0.f};

#define STAGE_C(k0, buf)                                                        \
  {                                                                             \
    gll16(wqkvb + (size_t)(m0 + r_a) * 2304 + t3 * 768 + (k0) + kc,             \
          &As[buf][w * 512]);                                                   \
    gll16(BT + (size_t)(n0 + r_a) * 768 + (k0) + kc, &Bs[buf][w * 512]);        \
  }

  STAGE_C(0, 0);
  for (int it = 0; it < 24; ++it) {
    __syncthreads();
    if (it < 23) STAGE_C((it + 1) * 32, (it + 1) & 1);
    const short* as = As[it & 1];
    const short* bs = Bs[it & 1];
    short8b afr[2], bfr[2];
#pragma unroll
    for (int mt = 0; mt < 2; ++mt)
      afr[mt] = *(const short8b*)&as[(moff + mt * 16 + tt) * 32 + q4 * 8];
#pragma unroll
    for (int nt = 0; nt < 2; ++nt)
      bfr[nt] = *(const short8b*)&bs[(noff + nt * 16 + tt) * 32 + q4 * 8];
#pragma unroll
    for (int mt = 0; mt < 2; ++mt)
#pragma unroll
      for (int nt = 0; nt < 2; ++nt)
        acc[mt][nt] = __builtin_amdgcn_mfma_f32_16x16x32_bf16(afr[mt], bfr[nt], acc[mt][nt], 0, 0, 0);
  }
#undef STAGE_C

  bf16* C = WcTb + (size_t)t3 * 768 * 768;
#pragma unroll
  for (int nt = 0; nt < 2; ++nt) {
    int n = n0 + noff + nt * 16 + tt;
#pragma unroll
    for (int mt = 0; mt < 2; ++mt) {
      int mb = m0 + moff + mt * 16 + q4 * 4;
      short4b v = {f2bs(acc[mt][nt][0]), f2bs(acc[mt][nt][1]),
                   f2bs(acc[mt][nt][2]), f2bs(acc[mt][nt][3])};
      *(short4b*)&C[(size_t)n * 768 + mb] = v;
    }
  }
}

// qh/kh/vh = xb @ Wc[t] + bias, scattered to [(b*12+h)][n][d] bf16 ; 128x64
__global__ __launch_bounds__(256) void k_proj_m(
    const bf16* __restrict__ xb, const bf16* __restrict__ WcTb,
    const float* __restrict__ bq, const float* __restrict__ bk,
    const float* __restrict__ bv,
    bf16* __restrict__ qh, bf16* __restrict__ kh, bf16* __restrict__ vh)
{
  __shared__ __align__(16) short As[2][128 * 32];
  __shared__ __align__(16) short Bs[2][64 * 32];
  const int t3 = blockIdx.z;
  const bf16* BT = WcTb + (size_t)t3 * 768 * 768;
  const float* bias = (t3 == 0) ? bq : (t3 == 1) ? bk : bv;
  bf16* dst = (t3 == 0) ? qh : (t3 == 1) ? kh : vh;
  const int m0 = blockIdx.y * 128, n0 = blockIdx.x * 64;
  const int tid = threadIdx.x, lane = tid & 63, w = tid >> 6;
  const int tt = lane & 15, q4 = lane >> 4;
  const int moff = (w & 1) * 64, noff = (w >> 1) * 32;
  const int r_a = tid >> 2, kc = (tid & 3) * 8;

  f32x4 acc[4][2];
#pragma unroll
  for (int i = 0; i < 4; ++i)
#pragma unroll
    for (int j = 0; j < 2; ++j) acc[i][j] = (f32x4){0.f, 0.f, 0.f, 0.f};

#define STAGE_P(k0, buf)                                                        \
  {                                                                             \
    gll16(xb + (size_t)(m0 + r_a) * 768 + (k0) + kc, &As[buf][w * 512]);        \
    gll16(xb + (size_t)(m0 + r_a + 64) * 768 + (k0) + kc,                       \
          &As[buf][2048 + w * 512]);                                            \
    gll16(BT + (size_t)(n0 + r_a) * 768 + (k0) + kc, &Bs[buf][w * 512]);        \
  }

  STAGE_P(0, 0);
  for (int it = 0; it < 24; ++it) {
    __syncthreads();
    if (it < 23) STAGE_P((it + 1) * 32, (it + 1) & 1);
    const short* as = As[it & 1];
    const short* bs = Bs[it & 1];
    short8b afr[4], bfr[2];
#pragma unroll
    for (int mt = 0; mt < 4; ++mt)
      afr[mt] = *(const short8b*)&as[(moff + mt * 16 + tt) * 32 + q4 * 8];
#pragma unroll
    for (int nt = 0; nt < 2; ++nt)
      bfr[nt] = *(const short8b*)&bs[(noff + nt * 16 + tt) * 32 + q4 * 8];
#pragma unroll
    for (int mt = 0; mt < 4; ++mt)
#pragma unroll
      for (int nt = 0; nt < 2; ++nt)
        acc[mt][nt] = __builtin_amdgcn_mfma_f32_16x16x32_bf16(afr[mt], bfr[nt], acc[mt][nt], 0, 0, 0);
  }
#undef STAGE_P

#pragma unroll
  for (int nt = 0; nt < 2; ++nt) {
    int c = n0 + noff + nt * 16 + tt;
    float bvv = bias[c];
    int h = c >> 6, d = c & 63;
#pragma unroll
    for (int mt = 0; mt < 4; ++mt) {
#pragma unroll
      for (int r = 0; r < 4; ++r) {
        int m = m0 + moff + mt * 16 + q4 * 4 + r;
        dst[(((size_t)((m >> 8) * 12 + h)) << 14) + ((m & 255) << 6) + d] =
            __float2bfloat16(acc[mt][nt][r] + bvv);
      }
    }
  }
}

// out = gather(attno) @ wo + bo (fp32 out) ; 64x64 tile
__global__ __launch_bounds__(256) void k_out_m(
    const bf16* __restrict__ attno, const bf16* __restrict__ woT,
    const float* __restrict__ bo, float* __restrict__ out)
{
  __shared__ __align__(16) short As[2][64 * 32];
  __shared__ __align__(16) short Bs[2][64 * 32];
  const int m0 = blockIdx.y * 64, n0 = blockIdx.x * 64;
  const int tid = threadIdx.x, lane = tid & 63, w = tid >> 6;
  const int tt = lane & 15, q4 = lane >> 4;
  const int moff = (w & 1) * 32, noff = (w >> 1) * 32;
  const int r_a = tid >> 2, kc = (tid & 3) * 8;
  const int m_a0 = m0 + r_a;

  f32x4 acc[2][2];
#pragma unroll
  for (int i = 0; i < 2; ++i)
#pragma unroll
    for (int j = 0; j < 2; ++j) acc[i][j] = (f32x4){0.f, 0.f, 0.f, 0.f};

#define STAGE_O(k0, buf)                                                        \
  {                                                                             \
    int k = (k0) + kc;                                                          \
    gll16(attno + (((size_t)((m_a0 >> 8) * 12 + (k >> 6))) << 14) +             \
              ((m_a0 & 255) << 6) + (k & 63),                                   \
          &As[buf][w * 512]);                                                   \
    gll16(woT + (size_t)(n0 + r_a) * 768 + k, &Bs[buf][w * 512]);               \
  }

  STAGE_O(0, 0);
  for (int it = 0; it < 24; ++it) {
    __syncthreads();
    if (it < 23) STAGE_O((it + 1) * 32, (it + 1) & 1);
    const short* as = As[it & 1];
    const short* bs = Bs[it & 1];
    short8b afr[2], bfr[2];
#pragma unroll
    for (int mt = 0; mt < 2; ++mt)
      afr[mt] = *(const short8b*)&as[(moff + mt * 16 + tt) * 32 + q4 * 8];
#pragma unroll
    for (int nt = 0; nt < 2; ++nt)
      bfr[nt] = *(const short8b*)&bs[(noff + nt * 16 + tt) * 32 + q4 * 8];
#pragma unroll
    for (int mt = 0; mt < 2; ++mt)
#pragma unroll
      for (int nt = 0; nt < 2; ++nt)
        acc[mt][nt] = __builtin_amdgcn_mfma_f32_16x16x32_bf16(afr[mt], bfr[nt], acc[mt][nt], 0, 0, 0);
  }
#undef STAGE_O

#pragma unroll
  for (int nt = 0; nt < 2; ++nt) {
    int c = n0 + noff + nt * 16 + tt;
    float bvv = bo[c];
#pragma unroll
    for (int mt = 0; mt < 2; ++mt)
#pragma unroll
      for (int r = 0; r < 4; ++r) {
        int m = m0 + moff + mt * 16 + q4 * 4 + r;
        out[(size_t)m * 768 + c] = acc[mt][nt][r] + bvv;
      }
  }
}

// ---------------------------------------------------------------------------
// PRIMARY path: SAT in LDS + materialize pooled areas.
// K-pass band-sliding with log2e FOLDED into the mean constants (Karea
// holds k_mean * log2e so attention uses raw v_exp_f32 = 2^x directly).
// Pad areas [2025,2048): Karea = exact 0 (=> s=0, p=1 in attn; corrected
// by l -= 23 there), VareaT = exact 0 (no O contamination).
// V-pass: it-outer loop hoists the rectG load + corner rescale (r10).
// ---------------------------------------------------------------------------
__global__ __launch_bounds__(1024) void k_area_pre(
    const bf16* __restrict__ kh, const bf16* __restrict__ vh,
    const int4* __restrict__ rectG, const float* __restrict__ invG,
    bf16* __restrict__ Karea, bf16* __restrict__ VareaT)
{
  __shared__ float sat[17 * 17 * 65];
  int bh = blockIdx.x >> 1;
  bool isv = blockIdx.x & 1;
  const bf16* src = (isv ? vh : kh) + ((size_t)bh << 14);
  int tid = threadIdx.x;
  int d = tid & 63;
  int row = tid >> 6;
  {
    float run = 0.f;
    sat[((row + 1) * 17) * 65 + d] = 0.f;
#pragma unroll
    for (int xx = 0; xx < 16; ++xx) {
      run += b2f(src[(row * 16 + xx) * 64 + d]);
      sat[((row + 1) * 17 + (xx + 1)) * 65 + d] = run;
    }
    if (row == 0) {
#pragma unroll
      for (int xx = 0; xx < 17; ++xx) sat[xx * 65 + d] = 0.f;
    }
  }
  __syncthreads();
  {
    int x = row + 1;
    float run = 0.f;
#pragma unroll
    for (int y = 1; y <= 16; ++y) {
      run += sat[(y * 17 + x) * 65 + d];
      sat[(y * 17 + x) * 65 + d] = run;
    }
  }
  __syncthreads();
  if (!isv) {
    // K band-sliding: wave = (y,ah) combo (45 total), lane = d.
    bf16* out = Karea + ((size_t)bh << 17);   // bh*2048*64
    for (int c = row; c < 45; c += 16) {
      int ah, y;
      if (c < 16)      { ah = 1; y = c; }
      else if (c < 31) { ah = 2; y = c - 16; }
      else             { ah = 3; y = c - 31; }
      int b1, b2, b3;
      if (ah == 1)      { b1 = 0;    b2 = 256;  b3 = 496;  }
      else if (ah == 2) { b1 = 720;  b2 = 960;  b3 = 1185; }
      else              { b1 = 1395; b2 = 1619; b3 = 1829; }
      float V[17];
#pragma unroll
      for (int x = 0; x < 17; ++x)
        V[x] = sat[((y + ah) * 17 + x) * 65 + d] - sat[(y * 17 + x) * 65 + d];
      {
        int b = b1 + y * 16;
        float iv = L2E / (float)ah;
#pragma unroll
        for (int x = 0; x < 16; ++x)
          out[(size_t)(b + x) * 64 + d] = __float2bfloat16((V[x + 1] - V[x]) * iv);
      }
      {
        int b = b2 + y * 15;
        float iv = L2E / (float)(2 * ah);
#pragma unroll
        for (int x = 0; x < 15; ++x)
          out[(size_t)(b + x) * 64 + d] = __float2bfloat16((V[x + 2] - V[x]) * iv);
      }
      {
        int b = b3 + y * 14;
        float iv = L2E / (float)(3 * ah);
#pragma unroll
        for (int x = 0; x < 14; ++x)
          out[(size_t)(b + x) * 64 + d] = __float2bfloat16((V[x + 3] - V[x]) * iv);
      }
    }
    if (row == 15) {
      for (int m = NAREA; m < NAREA_PAD; ++m)
        out[(size_t)m * 64 + d] = __float2bfloat16(0.f);
    }
  } else {
    // V: sum-pooled, transposed [it][d][m]; lanes span m -> coalesced 2B
    // stores. it-outer: one rectG load + corner rescale per (it,mcol).
    int mcol = tid & 63;
    int r16 = tid >> 6;             // 0..15
    bf16* out = VareaT + ((size_t)bh << 17);
    for (int it = 0; it < 32; ++it) {
      int4 rc = rectG[it * 64 + mcol];
      int cx = rc.x + (rc.x >> 6), cy = rc.y + (rc.y >> 6);
      int cz = rc.z + (rc.z >> 6), cw = rc.w + (rc.w >> 6);
#pragma unroll
      for (int j = 0; j < 4; ++j) {
        int dd = r16 + j * 16;
        float df = sat[cw + dd] - sat[cy + dd] - sat[cz + dd] + sat[cx + dd];
        out[(((size_t)it << 6) + dd) * 64 + mcol] = __float2bfloat16(df);
      }
    }
  }
}

// ---------------------------------------------------------------------------
// PRIMARY attention (r11 + maskless pads): 256-thr / 4-wave, 32 q/wave,
// area-split 2x, grid (192,2,2) = 768 blocks = 3/CU, additive partials.
// p = v_exp_f32(s) directly (log2e pre-folded into Karea).
// NO pad masking in the hot loop: K pads are exact 0 => s=0 => p=1 exactly;
// V pads are exact 0 => O unaffected; l over-counts by exactly 23.0 per
// query in the ahalf=1 blocks -> subtract after the reduction.
// ---------------------------------------------------------------------------
__global__ __launch_bounds__(256, 4) void k_attn_g(
    const bf16* __restrict__ qh, const bf16* __restrict__ Karea,
    const bf16* __restrict__ VareaT,
    float* __restrict__ Op0, float* __restrict__ Op1,
    float* __restrict__ lp0, float* __restrict__ lp1)
{
  __shared__ __align__(16) short aK2[2][64 * 80];
  __shared__ __align__(16) short aVt2[2][64 * 80];

  const int tid = threadIdx.x;
  const int w = tid >> 6;            // 0..3
  const int lane = tid & 63;
  const int t = lane & 15;
  const int q4 = lane >> 4;
  const int bh = blockIdx.x;
  const int Q0 = blockIdx.y * 128;
  const int it0 = blockIdx.z * 16;   // area half: tiles [it0, it0+16)
  const int rbase = (t & 12) * 2 + (t & 3);

  const bf16* Kb = Karea + ((size_t)bh << 17);
  const bf16* Vb = VareaT + ((size_t)bh << 17);
  const bf16* qrowA = qh + ((size_t)bh << 14) + (size_t)(Q0 + w * 32 + t) * 64;
  const bf16* qrowB = qrowA + 16 * 64;

  short8b qfA0 = *(const short8b*)(qrowA + q4 * 8);
  short8b qfA1 = *(const short8b*)(qrowA + 32 + q4 * 8);
  short8b qfB0 = *(const short8b*)(qrowB + q4 * 8);
  short8b qfB1 = *(const short8b*)(qrowB + 32 + q4 * 8);

  f32x4 OA[4], OB[4];
#pragma unroll
  for (int i = 0; i < 4; ++i) {
    OA[i] = (f32x4){0.f, 0.f, 0.f, 0.f};
    OB[i] = (f32x4){0.f, 0.f, 0.f, 0.f};
  }
  float lA = 0.f, lB = 0.f;

  const int a8 = tid >> 2;           // 0..63: area slot (K) / d row (V)
  const int c8 = (tid & 3) * 16;     // col start (elements); each thr 2x8

  {
    size_t off = ((size_t)(it0 * 64 + a8) << 6) + c8;
    short8b k0a = *(const short8b*)&Kb[off];
    short8b k0b = *(const short8b*)&Kb[off + 8];
    short8b v0a = *(const short8b*)&Vb[off];
    short8b v0b = *(const short8b*)&Vb[off + 8];
    *(short8b*)&aK2[0][a8 * 80 + c8] = k0a;
    *(short8b*)&aK2[0][a8 * 80 + c8 + 8] = k0b;
    *(short8b*)&aVt2[0][a8 * 80 + c8] = v0a;
    *(short8b*)&aVt2[0][a8 * 80 + c8 + 8] = v0b;
  }

  for (int it = it0; it < it0 + 16; ++it) {
    short8b kna, knb, vna, vnb;
    if (it + 1 < it0 + 16) {
      size_t off = ((size_t)((it + 1) * 64 + a8) << 6) + c8;
      kna = *(const short8b*)&Kb[off];
      knb = *(const short8b*)&Kb[off + 8];
      vna = *(const short8b*)&Vb[off];
      vnb = *(const short8b*)&Vb[off + 8];
    }
    __syncthreads();
    const short* aK = aK2[it & 1];
    const short* aVt = aVt2[it & 1];
    if (it + 1 < it0 + 16) {
      short* aKn = aK2[(it + 1) & 1];
      short* aVtn = aVt2[(it + 1) & 1];
      *(short8b*)&aKn[a8 * 80 + c8] = kna;
      *(short8b*)&aKn[a8 * 80 + c8 + 8] = knb;
      *(short8b*)&aVtn[a8 * 80 + c8] = vna;
      *(short8b*)&aVtn[a8 * 80 + c8 + 8] = vnb;
    }

    union { short8b v; unsigned u[4]; } apvA[2], apvB[2];
#pragma unroll
    for (int at = 0; at < 4; ++at) {
      int row = rbase + (at & 1) * 4 + (at >> 1) * 32;
      short8b af0 = *(const short8b*)&aK[row * 80 + q4 * 8];
      short8b af1 = *(const short8b*)&aK[row * 80 + 32 + q4 * 8];
      {
        f32x4 s = (f32x4){0.f, 0.f, 0.f, 0.f};
        s = __builtin_amdgcn_mfma_f32_16x16x32_bf16(af0, qfA0, s, 0, 0, 0);
        s = __builtin_amdgcn_mfma_f32_16x16x32_bf16(af1, qfA1, s, 0, 0, 0);
        float p[4];
#pragma unroll
        for (int r = 0; r < 4; ++r) p[r] = __builtin_amdgcn_exp2f(s[r]);
        lA += (p[0] + p[1]) + (p[2] + p[3]);
        unsigned lo = ((unsigned)(unsigned short)f2bs(p[1]) << 16) |
                      (unsigned short)f2bs(p[0]);
        unsigned hi = ((unsigned)(unsigned short)f2bs(p[3]) << 16) |
                      (unsigned short)f2bs(p[2]);
        apvA[at >> 1].u[(at & 1) * 2 + 0] = lo;
        apvA[at >> 1].u[(at & 1) * 2 + 1] = hi;
      }
      {
        f32x4 s = (f32x4){0.f, 0.f, 0.f, 0.f};
        s = __builtin_amdgcn_mfma_f32_16x16x32_bf16(af0, qfB0, s, 0, 0, 0);
        s = __builtin_amdgcn_mfma_f32_16x16x32_bf16(af1, qfB1, s, 0, 0, 0);
        float p[4];
#pragma unroll
        for (int r = 0; r < 4; ++r) p[r] = __builtin_amdgcn_exp2f(s[r]);
        lB += (p[0] + p[1]) + (p[2] + p[3]);
        unsigned lo = ((unsigned)(unsigned short)f2bs(p[1]) << 16) |
                      (unsigned short)f2bs(p[0]);
        unsigned hi = ((unsigned)(unsigned short)f2bs(p[3]) << 16) |
                      (unsigned short)f2bs(p[2]);
        apvB[at >> 1].u[(at & 1) * 2 + 0] = lo;
        apvB[at >> 1].u[(at & 1) * 2 + 1] = hi;
      }
    }
#pragma unroll
    for (int nt = 0; nt < 4; ++nt) {
      short8b vf0 = *(const short8b*)&aVt[(nt * 16 + t) * 80 + q4 * 8];
      short8b vf1 = *(const short8b*)&aVt[(nt * 16 + t) * 80 + 32 + q4 * 8];
      OA[nt] = __builtin_amdgcn_mfma_f32_16x16x32_bf16(apvA[0].v, vf0, OA[nt], 0, 0, 0);
      OA[nt] = __builtin_amdgcn_mfma_f32_16x16x32_bf16(apvA[1].v, vf1, OA[nt], 0, 0, 0);
      OB[nt] = __builtin_amdgcn_mfma_f32_16x16x32_bf16(apvB[0].v, vf0, OB[nt], 0, 0, 0);
      OB[nt] = __builtin_amdgcn_mfma_f32_16x16x32_bf16(apvB[1].v, vf1, OB[nt], 0, 0, 0);
    }
  }

  lA += __shfl_xor(lA, 16, 64);
  lA += __shfl_xor(lA, 32, 64);
  lB += __shfl_xor(lB, 16, 64);
  lB += __shfl_xor(lB, 32, 64);

  // pad correction: 23 pad areas contributed exp2(0)=1 each (ahalf=1 only)
  if (blockIdx.z) { lA -= 23.0f; lB -= 23.0f; }

  float* lp = blockIdx.z ? lp1 : lp0;
  float* Op = blockIdx.z ? Op1 : Op0;
  if (q4 == 0) {
    lp[(bh << 8) + Q0 + w * 32 + t] = lA;
    lp[(bh << 8) + Q0 + w * 32 + 16 + t] = lB;
  }
  float* Ob = Op + (((size_t)(bh << 8) + Q0 + w * 32) << 6);
#pragma unroll
  for (int r = 0; r < 4; ++r) {
    int qr = q4 * 4 + r;
#pragma unroll
    for (int nt = 0; nt < 4; ++nt) {
      Ob[qr * 64 + nt * 16 + t] = OA[nt][r];
      Ob[(16 + qr) * 64 + nt * 16 + t] = OB[nt][r];
    }
  }
}

// ---------------------------------------------------------------------------
// Combine area-half partials + (folded) wo transpose-cast.
// blocks [0,3072): attno = (O0+O1)/(l0+l1); blocks [3072,3648): tcast wo.
// ---------------------------------------------------------------------------
__global__ __launch_bounds__(256) void k_norm2t(
    const float* __restrict__ Op0, const float* __restrict__ Op1,
    const float* __restrict__ lp0, const float* __restrict__ lp1,
    bf16* __restrict__ attno,
    const float* __restrict__ wo, bf16* __restrict__ woT)
{
  if (blockIdx.x < 3072) {
    int i = (blockIdx.x * 256 + threadIdx.x) * 4;
    f32x4 a = *(const f32x4*)(Op0 + i);
    f32x4 b = *(const f32x4*)(Op1 + i);
    int q = i >> 6;
    float invl = 1.0f / (lp0[q] + lp1[q]);
    short4b s = {f2bs((a[0] + b[0]) * invl), f2bs((a[1] + b[1]) * invl),
                 f2bs((a[2] + b[2]) * invl), f2bs((a[3] + b[3]) * invl)};
    *(short4b*)(attno + i) = s;
    return;
  }
  __shared__ float tile[32][33];
  int b = blockIdx.x - 3072;
  int bxx = b % 24, byy = b / 24;
  int r0 = byy * 32, c0 = bxx * 32;
  int lx = threadIdx.x & 31, ly = threadIdx.x >> 5;
#pragma unroll
  for (int yy = 0; yy < 4; ++yy)
    tile[ly + yy * 8][lx] = wo[(size_t)(r0 + ly + yy * 8) * 768 + c0 + lx];
  __syncthreads();
#pragma unroll
  for (int yy = 0; yy < 4; ++yy)
    woT[(size_t)(c0 + ly + yy * 8) * 768 + r0 + lx] =
        __float2bfloat16(tile[lx][ly + yy * 8]);
}

// ---------------------------------------------------------------------------
// FALLBACK path (ws too small for materialized areas): round-0 verbatim.
// ---------------------------------------------------------------------------
__global__ __launch_bounds__(1024) void k_integral_p(
    const bf16* __restrict__ kh, const bf16* __restrict__ vh,
    float* __restrict__ Ik, float* __restrict__ Iv)
{
  __shared__ float sat[17 * 17 * 64];
  int bh = blockIdx.x >> 1;
  bool isv = blockIdx.x & 1;
  const bf16* src = (isv ? vh : kh) + ((size_t)bh << 14);
  float* dst = (isv ? Iv : Ik) + (size_t)bh * 18496;
  int tid = threadIdx.x;
  int d = tid & 63;
  int row = tid >> 6;
  {
    float run = 0.f;
    sat[((row + 1) * 17) * 64 + d] = 0.f;
#pragma unroll
    for (int xx = 0; xx < 16; ++xx) {
      run += b2f(src[(row * 16 + xx) * 64 + d]);
      sat[((row + 1) * 17 + (xx + 1)) * 64 + d] = run;
    }
    if (row == 0) {
#pragma unroll
      for (int xx = 0; xx < 17; ++xx) sat[xx * 64 + d] = 0.f;
    }
  }
  __syncthreads();
  {
    int x = row + 1;
    float run = 0.f;
#pragma unroll
    for (int y = 1; y <= 16; ++y) {
      run += sat[(y * 17 + x) * 64 + d];
      sat[(y * 17 + x) * 64 + d] = run;
    }
  }
  __syncthreads();
  for (int i = tid; i < 18496; i += 1024) dst[i] = sat[i];
}

__global__ __launch_bounds__(1024) void k_attn_m(
    const bf16* __restrict__ qh, const float* __restrict__ Ik,
    const float* __restrict__ Iv, const int4* __restrict__ rectG,
    const float* __restrict__ invG, bf16* __restrict__ attno)
{
  __shared__ __align__(16) short aK2[2][64 * 80];
  __shared__ __align__(16) short aVt2[2][64 * 72];

  const int tid = threadIdx.x;
  const int lane = tid & 63;
  const int w = tid >> 6;
  const int t = lane & 15;
  const int q4 = lane >> 4;
  const int bh = blockIdx.x;
  const int rbase = (t & 12) * 2 + (t & 3);

  const float* Ikb = Ik + (size_t)bh * 18496;
  const float* Ivb = Iv + (size_t)bh * 18496;
  const bf16* qbase = qh + ((size_t)bh << 14);

  short8b qf0 = *(const short8b*)(qbase + (w * 16 + t) * 64 + q4 * 8);
  short8b qf1 = *(const short8b*)(qbase + (w * 16 + t) * 64 + 32 + q4 * 8);

  f32x4 O[4];
#pragma unroll
  for (int i = 0; i < 4; ++i) O[i] = (f32x4){0.f, 0.f, 0.f, 0.f};
  float l = 0.f;

  {
    short* aK = aK2[0];
    short* aVt = aVt2[0];
    short vp[4];
#pragma unroll
    for (int i = 0; i < 4; ++i) {
      int j = w * 4 + i;
      int4 rc = rectG[j];
      float iv = invG[j];
      float kc = Ikb[rc.w + lane] - Ikb[rc.y + lane] - Ikb[rc.z + lane] + Ikb[rc.x + lane];
      float vc = Ivb[rc.w + lane] - Ivb[rc.y + lane] - Ivb[rc.z + lane] + Ivb[rc.x + lane];
      aK[j * 80 + lane] = f2bs(kc * iv);
      vp[i] = f2bs(vc);
    }
    *(short4b*)&aVt[lane * 72 + w * 4] = (short4b){vp[0], vp[1], vp[2], vp[3]};
  }

  float kcr[4], vcr[4], ivr[4];
  for (int it = 0; it < 32; ++it) {
    if (it + 1 < 32) {
      int t0n = (it + 1) * 64;
#pragma unroll
      for (int i = 0; i < 4; ++i) {
        int j = t0n + w * 4 + i;
        int4 rc = rectG[j];
        ivr[i] = invG[j];
        kcr[i] = Ikb[rc.w + lane] - Ikb[rc.y + lane] - Ikb[rc.z + lane] + Ikb[rc.x + lane];
        vcr[i] = Ivb[rc.w + lane] - Ivb[rc.y + lane] - Ivb[rc.z + lane] + Ivb[rc.x + lane];
      }
    }
    __syncthreads();
    const short* aK = aK2[it & 1];
    const short* aVt = aVt2[it & 1];
    if (it + 1 < 32) {
      short* aKn = aK2[(it + 1) & 1];
      short* aVtn = aVt2[(it + 1) & 1];
      short vp[4];
#pragma unroll
      for (int i = 0; i < 4; ++i) {
        aKn[(w * 4 + i) * 80 + lane] = f2bs(kcr[i] * ivr[i]);
        vp[i] = f2bs(vcr[i]);
      }
      *(short4b*)&aVtn[lane * 72 + w * 4] = (short4b){vp[0], vp[1], vp[2], vp[3]};
    }

    const int t0 = it * 64;
    const bool edge = (t0 + 64 > NAREA);
    union { short8b v; unsigned u[4]; } apv[2];
#pragma unroll
    for (int at = 0; at < 4; ++at) {
      int row = rbase + (at & 1) * 4 + (at >> 1) * 32;
      short8b af0 = *(const short8b*)&aK[row * 80 + q4 * 8];
      short8b af1 = *(const short8b*)&aK[row * 80 + 32 + q4 * 8];
      f32x4 s = (f32x4){0.f, 0.f, 0.f, 0.f};
      s = __builtin_amdgcn_mfma_f32_16x16x32_bf16(af0, qf0, s, 0, 0, 0);
      s = __builtin_amdgcn_mfma_f32_16x16x32_bf16(af1, qf1, s, 0, 0, 0);
      int abase = t0 + (at >> 1) * 32 + q4 * 8 + (at & 1) * 4;
      float p[4];
#pragma unroll
      for (int r = 0; r < 4; ++r) {
        p[r] = __expf(s[r]);
        if (edge && (abase + r >= NAREA)) p[r] = 0.f;
      }
      l += (p[0] + p[1]) + (p[2] + p[3]);
      unsigned lo = ((unsigned)(unsigned short)f2bs(p[1]) << 16) |
                    (unsigned short)f2bs(p[0]);
      unsigned hi = ((unsigned)(unsigned short)f2bs(p[3]) << 16) |
                    (unsigned short)f2bs(p[2]);
      apv[at >> 1].u[(at & 1) * 2 + 0] = lo;
      apv[at >> 1].u[(at & 1) * 2 + 1] = hi;
    }
#pragma unroll
    for (int nt = 0; nt < 4; ++nt) {
      short8b vf0 = *(const short8b*)&aVt[(nt * 16 + t) * 72 + q4 * 8];
      short8b vf1 = *(const short8b*)&aVt[(nt * 16 + t) * 72 + 32 + q4 * 8];
      O[nt] = __builtin_amdgcn_mfma_f32_16x16x32_bf16(apv[0].v, vf0, O[nt], 0, 0, 0);
      O[nt] = __builtin_amdgcn_mfma_f32_16x16x32_bf16(apv[1].v, vf1, O[nt], 0, 0, 0);
    }
  }

  l += __shfl_xor(l, 16, 64);
  l += __shfl_xor(l, 32, 64);

  bf16* ob = attno + ((size_t)bh << 14);
#pragma unroll
  for (int r = 0; r < 4; ++r) {
    int qrow = q4 * 4 + r;
    float invl = 1.0f / __shfl(l, qrow, 64);
#pragma unroll
    for (int nt = 0; nt < 4; ++nt)
      ob[(w * 16 + qrow) * 64 + nt * 16 + t] = __float2bfloat16(O[nt][r] * invl);
  }
}

extern "C" void kernel_launch(void* const* d_in, const int* in_sizes, int n_in,
                              void* d_out, int out_size, void* d_ws, size_t ws_size,
                              hipStream_t stream) {
  const float* x    = (const float*)d_in[0];
  const float* wqkv = (const float*)d_in[1];
  const float* wq   = (const float*)d_in[2];
  const float* bq   = (const float*)d_in[3];
  const float* wk   = (const float*)d_in[4];
  const float* bk   = (const float*)d_in[5];
  const float* wv   = (const float*)d_in[6];
  const float* bv   = (const float*)d_in[7];
  const float* wo   = (const float*)d_in[8];
  const float* bo   = (const float*)d_in[9];
  float* out = (float*)d_out;

  char* ws = (char*)d_ws;
  char* ob = (char*)d_out;
  const size_t WC_B = 7077888;   // zone A size
  const size_t QH_B = 6291456;   // bf16 [192][256][64]
  const size_t AREA_B = 50331648; // bf16 [192][2048][64]

  // d_out as scratch: xb + WcTb (dead after k_proj_m), then Op0 (f32 attn
  // partial, = out_size), consumed by k_norm2t before k_out_m writes out.
  bf16* xb    = (bf16*)ob;                  // [0, 6291456)
  bf16* WcTb  = (bf16*)(ob + QH_B);         // [6291456, 9830400)
  float* Op0  = (float*)ob;                 // full 12582912 B
  // ws zone A: attno [0,6291456), rectG/invG, lp0/lp1
  bf16* attno = (bf16*)ws;
  int4*  rectG = (int4*)(ws + QH_B);             // [6291456, 6324224)
  float* invG  = (float*)(ws + QH_B + 32768);    // [6324224, 6332416)
  float* lp0   = (float*)(ws + QH_B + 40960);    // [6332416, 6529024)
  float* lp1   = lp0 + 49152;                    // [6529024, 6725632) < WC_B
  // qh/kh/vh
  bf16* qh = (bf16*)(ws + WC_B);
  bf16* kh = (bf16*)(ws + WC_B + QH_B);
  bf16* vh = (bf16*)(ws + WC_B + 2 * QH_B);
  // Op1 aliases kh+vh (dead after k_area_pre); exactly 2*QH_B = 12582912 B
  float* Op1 = (float*)(ws + WC_B + QH_B);
  // pre-k_proj aliases into (not-yet-written) qh/kh region
  bf16* wqkvb = (bf16*)(ws + WC_B);
  bf16* wqT   = (bf16*)(ws + WC_B + 3538944);
  bf16* wkT   = (bf16*)(ws + WC_B + 4718592);
  bf16* wvT   = (bf16*)(ws + WC_B + 5898240);
  // PRIMARY: materialized pooled areas (dead after attn; woT aliases here)
  bf16* Karea  = (bf16*)(ws + WC_B + 3 * QH_B);
  bf16* VareaT = (bf16*)(ws + WC_B + 3 * QH_B + AREA_B);
  // FALLBACK: SAT buffers (r0 layout, known fit at 54,362,112)
  float* Ik = (float*)(ws + WC_B + 3 * QH_B);
  float* Iv = Ik + 3551232;
  bf16* woT = (bf16*)(ws + WC_B + 3 * QH_B);

  const size_t REQ = WC_B + 3 * QH_B + 2 * AREA_B;  // 126,615,552
  const bool primary = (ws_size >= REQ);

  k_prep<<<dim3(6536), 256, 0, stream>>>(x, wqkv, wq, wk, wv, xb, wqkvb,
                                         wqT, wkT, wvT, rectG, invG);
  k_combine_m<<<dim3(12, 12, 3), 256, 0, stream>>>(wqkvb, wqT, wkT, wvT, WcTb);
  k_proj_m<<<dim3(12, 32, 3), 256, 0, stream>>>(xb, WcTb, bq, bk, bv, qh, kh, vh);
  if (primary) {
    k_area_pre<<<dim3(384), 1024, 0, stream>>>(kh, vh, rectG, invG, Karea, VareaT);
    k_attn_g<<<dim3(192, 2, 2), 256, 0, stream>>>(qh, Karea, VareaT,
                                                  Op0, Op1, lp0, lp1);
    // norm + wo transpose-cast fused (woT aliases dead Karea region)
    k_norm2t<<<dim3(3648), 256, 0, stream>>>(Op0, Op1, lp0, lp1, attno, wo, woT);
  } else {
    k_integral_p<<<dim3(384), 1024, 0, stream>>>(kh, vh, Ik, Iv);
    k_attn_m<<<dim3(192), 1024, 0, stream>>>(qh, Ik, Iv, rectG, invG, attno);
    k_tcast1<<<dim3(24, 24), 256, 0, stream>>>(wo, woT);
  }
  k_out_m<<<dim3(12, 64), 256, 0, stream>>>(attno, woT, bo, out);
}